// Round 1
// baseline (1811.101 us; speedup 1.0000x reference)
//
#include <hip/hip_runtime.h>
#include <cstdint>
#include <cstddef>

typedef __bf16 bf16_t;
typedef bf16_t bf16x8 __attribute__((ext_vector_type(8)));
typedef float f32x4 __attribute__((ext_vector_type(4)));

#define B_SZ    4
#define LSEQ    2048
#define DMODEL  1024
#define EDIM    2048
#define NSTATE  128
#define ZDIM    4419
#define ZPAD    4480
#define ROWS    (B_SZ*LSEQ)     /* 8192 */
#define EPSV    1e-5f

// ---------------- helpers ----------------
__device__ __forceinline__ float softplus_f(float x){
  return fmaxf(x, 0.f) + log1pf(expf(-fabsf(x)));
}
__device__ __forceinline__ float sigmoid_f(float x){ return 1.f/(1.f+expf(-x)); }
__device__ __forceinline__ float silu_f(float x){ return x/(1.f+expf(-x)); }

__device__ __forceinline__ void gload_lds16(const void* g, void* l){
  __builtin_amdgcn_global_load_lds(
      (const __attribute__((address_space(1))) void*)g,
      (__attribute__((address_space(3))) void*)l, 16, 0, 0);
}

__device__ __forceinline__ float blockReduce256(float v, float* red, int t){
  red[t] = v; __syncthreads();
  #pragma unroll
  for (int off = 128; off > 0; off >>= 1){
    if (t < off) red[t] += red[t+off];
    __syncthreads();
  }
  float r = red[0];
  __syncthreads();
  return r;
}

// ---------------- kernel 0: casts + zero accumulator ----------------
__global__ __launch_bounds__(256) void prep_kernel(
    const float* __restrict__ u, const float* __restrict__ win, const float* __restrict__ wout,
    bf16_t* __restrict__ ubf, bf16_t* __restrict__ winbf, bf16_t* __restrict__ woutbf,
    float* __restrict__ Asum)
{
  size_t i = (size_t)blockIdx.x*256 + threadIdx.x;
  if (i == 0) Asum[0] = 0.f;
  const size_t NU = (size_t)ROWS*DMODEL;       // 8388608
  const size_t NW = (size_t)ZPAD*DMODEL;       // 4587520
  const size_t NO = (size_t)DMODEL*EDIM;       // 2097152
  if (i < NU){ ubf[i] = (bf16_t)u[i]; return; }
  i -= NU;
  if (i < NW){
    size_t n = i >> 10;
    winbf[i] = (n < (size_t)ZDIM) ? (bf16_t)win[i] : (bf16_t)0.f;
    return;
  }
  i -= NW;
  if (i < NO) woutbf[i] = (bf16_t)wout[i];
}

// ---------------- kernel 1: GEMM1  z = u @ W_in^T, fused epilogue ----------------
// A: [8192,1024] bf16 row-major, W: [4480,1024] bf16 row-major (B^T layout).
// cols 0..2047 -> silu -> xbuf bf16 ; 2048..4095 -> silu -> gbuf bf16 ; 4096..4479 -> zs fp32
__global__ __launch_bounds__(256) void gemm1_kernel(
    const bf16_t* __restrict__ A, const bf16_t* __restrict__ W,
    bf16_t* __restrict__ xbuf, bf16_t* __restrict__ gbuf, float* __restrict__ zs)
{
  __shared__ bf16_t lA[128*32];
  __shared__ bf16_t lB[128*32];
  const int K = DMODEL;
  int tid = threadIdx.x;
  int wid = tid>>6, lane = tid&63;
  int wr = wid>>1, wc = wid&1;
  int m0 = blockIdx.y*128, n0 = blockIdx.x*128;

  f32x4 acc[4][4] = {};

  int crow = tid>>2;            // 0..63
  int ccol = (tid&3)*8;         // k element
  const bf16_t* gA0 = A + (size_t)(m0+crow)*K + ccol;
  const bf16_t* gB0 = W + (size_t)(n0+crow)*K + ccol;

  for (int k0 = 0; k0 < K; k0 += 32){
    gload_lds16(gA0 + k0,        lA + wid*512);
    gload_lds16(gA0 + 64*K + k0, lA + 2048 + wid*512);
    gload_lds16(gB0 + k0,        lB + wid*512);
    gload_lds16(gB0 + 64*K + k0, lB + 2048 + wid*512);
    __syncthreads();
    int lrow = lane&15, lk = (lane>>4)*8;
    bf16x8 af[4], bfr[4];
    #pragma unroll
    for (int m=0;m<4;++m) af[m]  = *(const bf16x8*)&lA[(wr*64+m*16+lrow)*32 + lk];
    #pragma unroll
    for (int n=0;n<4;++n) bfr[n] = *(const bf16x8*)&lB[(wc*64+n*16+lrow)*32 + lk];
    #pragma unroll
    for (int m=0;m<4;++m)
      #pragma unroll
      for (int n=0;n<4;++n)
        acc[m][n] = __builtin_amdgcn_mfma_f32_16x16x32_bf16(af[m], bfr[n], acc[m][n], 0,0,0);
    __syncthreads();
  }

  #pragma unroll
  for (int m=0;m<4;++m){
    int rowb = m0 + wr*64 + m*16 + ((lane>>4)<<2);
    #pragma unroll
    for (int n=0;n<4;++n){
      int col = n0 + wc*64 + n*16 + (lane&15);
      #pragma unroll
      for (int i=0;i<4;++i){
        float v = acc[m][n][i];
        int r = rowb + i;
        if (col < 2048)       xbuf[(size_t)r*EDIM + col]          = (bf16_t)silu_f(v);
        else if (col < 4096)  gbuf[(size_t)r*EDIM + (col-2048)]   = (bf16_t)silu_f(v);
        else                  zs[(size_t)r*384 + (col-4096)]      = v;
      }
    }
  }
}

// ---------------- kernel 2: per-token fuse ----------------
__global__ __launch_bounds__(256) void fuse_kernel(
    const bf16_t* __restrict__ xbuf, const float* __restrict__ zs,
    const float* __restrict__ wnB, const float* __restrict__ wnC,
    const float* __restrict__ Bb, const float* __restrict__ Cb,
    const float* __restrict__ dtb, const float* __restrict__ Alog,
    float* __restrict__ Bn, float* __restrict__ Cn, float* __restrict__ dtth,
    float* __restrict__ dts, float* __restrict__ alphas, float* __restrict__ lams,
    float* __restrict__ xbar, float* Asum)
{
  __shared__ float red[256];
  int r = blockIdx.x, t = threadIdx.x;

  // mean of silu(x) row (already silu'd, bf16)
  const bf16_t* xr = xbuf + (size_t)r*EDIM;
  bf16x8 xv = *(const bf16x8*)(xr + t*8);
  float s = 0.f;
  #pragma unroll
  for (int i=0;i<8;++i) s += (float)xv[i];
  float xs = blockReduce256(s, red, t);

  const float* zr = zs + (size_t)r*384;
  float dt  = softplus_f(zr[256] + dtb[0]);
  float Av  = -softplus_f(zr[257] + Alog[0]);
  float lam = sigmoid_f(zr[322]);
  float alpha = expf(dt*Av);

  if (t == 0){
    xbar[r]   = xs * (1.f/2048.f);
    dts[r]    = dt;
    alphas[r] = alpha;
    lams[r]   = lam;
    atomicAdd(Asum, Av);
  }
  if (t < 64) dtth[(size_t)r*64 + t] = dt * zr[258+t];

  float bv = (t < 128) ? zr[t]       : 0.f;
  float cv = (t < 128) ? zr[128+t]   : 0.f;
  float b2 = blockReduce256(bv*bv, red, t);
  float c2 = blockReduce256(cv*cv, red, t);
  if (t < 128){
    float rb = rsqrtf(b2*(1.f/128.f) + EPSV);
    float rc = rsqrtf(c2*(1.f/128.f) + EPSV);
    Bn[(size_t)r*128 + t] = bv*rb*wnB[t] + Bb[t];
    Cn[(size_t)r*128 + t] = cv*rc*wnC[t] + Cb[t];
  }
}

// ---------------- kernel 3: cumsum angles + RoPE (in place on Bn,Cn) ----------------
__global__ __launch_bounds__(64) void rope_kernel(
    const float* __restrict__ dtth, float* __restrict__ Bn, float* __restrict__ Cn)
{
  int b  = blockIdx.x >> 3;   // 0..3
  int ch = blockIdx.x & 7;    // 0..7 chunks of 256
  int d  = threadIdx.x;       // 0..63
  const float* base = dtth + (size_t)b*LSEQ*64 + d;
  float ca = 0.f;
  int l0 = ch*256;
  for (int l = 0; l < l0; ++l) ca += base[(size_t)l*64];
  for (int l = l0; l < l0+256; ++l){
    ca += base[(size_t)l*64];
    float sn, cs;
    sincosf(ca, &sn, &cs);
    size_t ro = ((size_t)b*LSEQ + l)*128;
    float b1 = Bn[ro+d], b2v = Bn[ro+64+d];
    Bn[ro+d]    = b1*cs - b2v*sn;
    Bn[ro+64+d] = b1*sn + b2v*cs;
    float c1 = Cn[ro+d], c2v = Cn[ro+64+d];
    Cn[ro+d]    = c1*cs - c2v*sn;
    Cn[ro+64+d] = c1*sn + c2v*cs;
  }
}

// ---------------- kernel 4: sequential SSM scan ----------------
__global__ __launch_bounds__(64) void scan_kernel(
    const float* __restrict__ dts, const float* __restrict__ alphas,
    const float* __restrict__ lams, const float* __restrict__ xbar,
    const float* __restrict__ Asum,
    const float* __restrict__ Bn, const float* __restrict__ Cn,
    float* __restrict__ outsv)
{
  int b = blockIdx.x;
  int n = threadIdx.x;  // handles state n and n+64
  float Abar = Asum[0] * (1.f/(float)ROWS);
  float s1 = 0.f, s2 = 0.f, xprev = 0.f;
  for (int l = 0; l < LSEQ; ++l){
    size_t r = (size_t)b*LSEQ + l;
    float dt = dts[r], lam = lams[r], al = alphas[r], xb = xbar[r];
    float um = lam*xb + (1.f-lam)*al*xprev;
    xprev = xb;
    float dA = expf(dt*Abar);
    float coef = dt*um;
    size_t ro = r*128;
    s1 = dA*s1 + coef*Bn[ro+n];
    s2 = dA*s2 + coef*Bn[ro+64+n];
    float p = s1*Cn[ro+n] + s2*Cn[ro+64+n];
    #pragma unroll
    for (int off = 32; off > 0; off >>= 1) p += __shfl_down(p, off);
    if (n == 0) outsv[r] = p;
  }
}

// ---------------- kernel 5: GEMM2  out = (outs * gate) @ W_out^T ----------------
__global__ __launch_bounds__(256) void gemm2_kernel(
    const bf16_t* __restrict__ A,   // [8192,2048] silu(gate) bf16
    const bf16_t* __restrict__ W,   // [1024,2048] bf16
    const float* __restrict__ outsv,
    float* __restrict__ out)
{
  __shared__ bf16_t lA[128*32];
  __shared__ bf16_t lB[128*32];
  const int K = EDIM;
  int tid = threadIdx.x;
  int wid = tid>>6, lane = tid&63;
  int wr = wid>>1, wc = wid&1;
  int m0 = blockIdx.y*128, n0 = blockIdx.x*128;

  f32x4 acc[4][4] = {};

  int crow = tid>>2;
  int ccol = (tid&3)*8;
  const bf16_t* gA0 = A + (size_t)(m0+crow)*K + ccol;
  const bf16_t* gB0 = W + (size_t)(n0+crow)*K + ccol;

  for (int k0 = 0; k0 < K; k0 += 32){
    gload_lds16(gA0 + k0,        lA + wid*512);
    gload_lds16(gA0 + 64*K + k0, lA + 2048 + wid*512);
    gload_lds16(gB0 + k0,        lB + wid*512);
    gload_lds16(gB0 + 64*K + k0, lB + 2048 + wid*512);
    __syncthreads();
    int lrow = lane&15, lk = (lane>>4)*8;
    bf16x8 af[4], bfr[4];
    #pragma unroll
    for (int m=0;m<4;++m) af[m]  = *(const bf16x8*)&lA[(wr*64+m*16+lrow)*32 + lk];
    #pragma unroll
    for (int n=0;n<4;++n) bfr[n] = *(const bf16x8*)&lB[(wc*64+n*16+lrow)*32 + lk];
    #pragma unroll
    for (int m=0;m<4;++m)
      #pragma unroll
      for (int n=0;n<4;++n)
        acc[m][n] = __builtin_amdgcn_mfma_f32_16x16x32_bf16(af[m], bfr[n], acc[m][n], 0,0,0);
    __syncthreads();
  }

  #pragma unroll
  for (int m=0;m<4;++m){
    int rowb = m0 + wr*64 + m*16 + ((lane>>4)<<2);
    #pragma unroll
    for (int n=0;n<4;++n){
      int col = n0 + wc*64 + n*16 + (lane&15);
      #pragma unroll
      for (int i=0;i<4;++i){
        int r = rowb + i;
        out[(size_t)r*DMODEL + col] = acc[m][n][i] * outsv[r];
      }
    }
  }
}

// ---------------- launch ----------------
extern "C" void kernel_launch(void* const* d_in, const int* in_sizes, int n_in,
                              void* d_out, int out_size, void* d_ws, size_t ws_size,
                              hipStream_t stream)
{
  const float* u    = (const float*)d_in[0];
  const float* W_in = (const float*)d_in[1];
  const float* wnB  = (const float*)d_in[2];
  const float* wnC  = (const float*)d_in[3];
  const float* Bb   = (const float*)d_in[4];
  const float* Cb   = (const float*)d_in[5];
  const float* dtb  = (const float*)d_in[6];
  const float* Alog = (const float*)d_in[7];
  const float* Wout = (const float*)d_in[8];
  float* out = (float*)d_out;
  char* ws = (char*)d_ws;

  constexpr size_t OFF_ASUM = 0;
  constexpr size_t OFF_UBF  = 256;
  constexpr size_t SZ_UBF   = (size_t)ROWS*DMODEL*2;
  constexpr size_t OFF_WIN  = OFF_UBF + SZ_UBF;
  constexpr size_t SZ_WIN   = (size_t)ZPAD*DMODEL*2;
  constexpr size_t OFF_WOUT = OFF_WIN + SZ_WIN;
  constexpr size_t SZ_WOUT  = (size_t)DMODEL*EDIM*2;
  constexpr size_t OFF_X    = OFF_WOUT + SZ_WOUT;
  constexpr size_t SZ_X     = (size_t)ROWS*EDIM*2;
  constexpr size_t OFF_G    = OFF_X + SZ_X;
  constexpr size_t OFF_ZS   = OFF_G + SZ_X;
  constexpr size_t SZ_ZS    = (size_t)ROWS*384*4;
  constexpr size_t OFF_BN   = OFF_ZS + SZ_ZS;
  constexpr size_t SZ_BN    = (size_t)ROWS*128*4;
  constexpr size_t OFF_CN   = OFF_BN + SZ_BN;
  constexpr size_t OFF_DTTH = OFF_CN + SZ_BN;
  constexpr size_t SZ_DTTH  = (size_t)ROWS*64*4;
  constexpr size_t OFF_DT   = OFF_DTTH + SZ_DTTH;
  constexpr size_t OFF_AL   = OFF_DT  + (size_t)ROWS*4;
  constexpr size_t OFF_LAM  = OFF_AL  + (size_t)ROWS*4;
  constexpr size_t OFF_XB   = OFF_LAM + (size_t)ROWS*4;
  constexpr size_t OFF_OUTS = OFF_XB  + (size_t)ROWS*4;

  float*  Asum   = (float*) (ws + OFF_ASUM);
  bf16_t* ubf    = (bf16_t*)(ws + OFF_UBF);
  bf16_t* winbf  = (bf16_t*)(ws + OFF_WIN);
  bf16_t* woutbf = (bf16_t*)(ws + OFF_WOUT);
  bf16_t* xbuf   = (bf16_t*)(ws + OFF_X);
  bf16_t* gbuf   = (bf16_t*)(ws + OFF_G);
  float*  zsb    = (float*) (ws + OFF_ZS);
  float*  Bn     = (float*) (ws + OFF_BN);
  float*  Cn     = (float*) (ws + OFF_CN);
  float*  dtth   = (float*) (ws + OFF_DTTH);
  float*  dts    = (float*) (ws + OFF_DT);
  float*  alphas = (float*) (ws + OFF_AL);
  float*  lams   = (float*) (ws + OFF_LAM);
  float*  xbar   = (float*) (ws + OFF_XB);
  float*  outsv  = (float*) (ws + OFF_OUTS);

  // 0) casts + zero Asum
  {
    size_t total = (size_t)ROWS*DMODEL + (size_t)ZPAD*DMODEL + (size_t)DMODEL*EDIM;
    int blocks = (int)((total + 255)/256);
    prep_kernel<<<blocks, 256, 0, stream>>>(u, W_in, Wout, ubf, winbf, woutbf, Asum);
  }
  // 1) GEMM1 + fused activation/split epilogue
  {
    dim3 g(ZPAD/128, ROWS/128);
    gemm1_kernel<<<g, 256, 0, stream>>>(ubf, winbf, xbuf, gbuf, zsb);
  }
  // 2) per-token fuse
  fuse_kernel<<<ROWS, 256, 0, stream>>>(xbuf, zsb, wnB, wnC, Bb, Cb, dtb, Alog,
                                        Bn, Cn, dtth, dts, alphas, lams, xbar, Asum);
  // 3) cumsum + rope
  rope_kernel<<<32, 64, 0, stream>>>(dtth, Bn, Cn);
  // 4) scan
  scan_kernel<<<B_SZ, 64, 0, stream>>>(dts, alphas, lams, xbar, Asum, Bn, Cn, outsv);
  // 5) GEMM2 + row-scale epilogue
  {
    dim3 g(DMODEL/128, ROWS/128);
    gemm2_kernel<<<g, 256, 0, stream>>>(gbuf, woutbf, outsv, out);
  }
}

// Round 2
// 416.743 us; speedup vs baseline: 4.3458x; 4.3458x over previous
//
#include <hip/hip_runtime.h>
#include <cstdint>
#include <cstddef>

typedef __bf16 bf16_t;
typedef bf16_t bf16x8 __attribute__((ext_vector_type(8)));
typedef float f32x4 __attribute__((ext_vector_type(4)));

#define B_SZ    4
#define LSEQ    2048
#define DMODEL  1024
#define EDIM    2048
#define NSTATE  128
#define ZDIM    4419
#define ZPAD    4480
#define ROWS    (B_SZ*LSEQ)     /* 8192 */
#define EPSV    1e-5f

#define SCHUNK  64              /* scan chunks per batch */
#define SCLEN   (LSEQ/SCHUNK)   /* 32 */
#define RCH     32              /* rope chunks per batch */
#define RCLEN   (LSEQ/RCH)      /* 64 */

// ---------------- helpers ----------------
__device__ __forceinline__ float softplus_f(float x){
  return fmaxf(x, 0.f) + log1pf(expf(-fabsf(x)));
}
__device__ __forceinline__ float sigmoid_f(float x){ return 1.f/(1.f+expf(-x)); }
__device__ __forceinline__ float silu_f(float x){ return x/(1.f+expf(-x)); }

__device__ __forceinline__ void gload_lds16(const void* g, void* l){
  __builtin_amdgcn_global_load_lds(
      (const __attribute__((address_space(1))) void*)g,
      (__attribute__((address_space(3))) void*)l, 16, 0, 0);
}

__device__ __forceinline__ float blockReduce256(float v, float* red, int t){
  red[t] = v; __syncthreads();
  #pragma unroll
  for (int off = 128; off > 0; off >>= 1){
    if (t < off) red[t] += red[t+off];
    __syncthreads();
  }
  float r = red[0];
  __syncthreads();
  return r;
}

// ---------------- kernel 0: casts + zero accumulator ----------------
__global__ __launch_bounds__(256) void prep_kernel(
    const float* __restrict__ u, const float* __restrict__ win, const float* __restrict__ wout,
    bf16_t* __restrict__ ubf, bf16_t* __restrict__ winbf, bf16_t* __restrict__ woutbf,
    float* __restrict__ Asum)
{
  size_t i = (size_t)blockIdx.x*256 + threadIdx.x;
  if (i == 0) Asum[0] = 0.f;
  const size_t NU = (size_t)ROWS*DMODEL;
  const size_t NW = (size_t)ZPAD*DMODEL;
  const size_t NO = (size_t)DMODEL*EDIM;
  if (i < NU){ ubf[i] = (bf16_t)u[i]; return; }
  i -= NU;
  if (i < NW){
    size_t n = i >> 10;
    winbf[i] = (n < (size_t)ZDIM) ? (bf16_t)win[i] : (bf16_t)0.f;
    return;
  }
  i -= NW;
  if (i < NO) woutbf[i] = (bf16_t)wout[i];
}

// ---------------- kernel 1: GEMM1  z = u @ W_in^T, fused epilogue ----------------
__global__ __launch_bounds__(256) void gemm1_kernel(
    const bf16_t* __restrict__ A, const bf16_t* __restrict__ W,
    bf16_t* __restrict__ xbuf, bf16_t* __restrict__ gbuf, float* __restrict__ zs)
{
  __shared__ bf16_t lA[128*32];
  __shared__ bf16_t lB[128*32];
  const int K = DMODEL;
  int tid = threadIdx.x;
  int wid = tid>>6, lane = tid&63;
  int wr = wid>>1, wc = wid&1;
  int m0 = blockIdx.y*128, n0 = blockIdx.x*128;

  f32x4 acc[4][4] = {};

  int crow = tid>>2;
  int ccol = (tid&3)*8;
  const bf16_t* gA0 = A + (size_t)(m0+crow)*K + ccol;
  const bf16_t* gB0 = W + (size_t)(n0+crow)*K + ccol;

  for (int k0 = 0; k0 < K; k0 += 32){
    gload_lds16(gA0 + k0,        lA + wid*512);
    gload_lds16(gA0 + 64*K + k0, lA + 2048 + wid*512);
    gload_lds16(gB0 + k0,        lB + wid*512);
    gload_lds16(gB0 + 64*K + k0, lB + 2048 + wid*512);
    __syncthreads();
    int lrow = lane&15, lk = (lane>>4)*8;
    bf16x8 af[4], bfr[4];
    #pragma unroll
    for (int m=0;m<4;++m) af[m]  = *(const bf16x8*)&lA[(wr*64+m*16+lrow)*32 + lk];
    #pragma unroll
    for (int n=0;n<4;++n) bfr[n] = *(const bf16x8*)&lB[(wc*64+n*16+lrow)*32 + lk];
    #pragma unroll
    for (int m=0;m<4;++m)
      #pragma unroll
      for (int n=0;n<4;++n)
        acc[m][n] = __builtin_amdgcn_mfma_f32_16x16x32_bf16(af[m], bfr[n], acc[m][n], 0,0,0);
    __syncthreads();
  }

  #pragma unroll
  for (int m=0;m<4;++m){
    int rowb = m0 + wr*64 + m*16 + ((lane>>4)<<2);
    #pragma unroll
    for (int n=0;n<4;++n){
      int col = n0 + wc*64 + n*16 + (lane&15);
      #pragma unroll
      for (int i=0;i<4;++i){
        float v = acc[m][n][i];
        int r = rowb + i;
        if (col < 2048)       xbuf[(size_t)r*EDIM + col]          = (bf16_t)silu_f(v);
        else if (col < 4096)  gbuf[(size_t)r*EDIM + (col-2048)]   = (bf16_t)silu_f(v);
        else                  zs[(size_t)r*384 + (col-4096)]      = v;
      }
    }
  }
}

// ---------------- kernel 2: per-token fuse ----------------
__global__ __launch_bounds__(256) void fuse_kernel(
    const bf16_t* __restrict__ xbuf, const float* __restrict__ zs,
    const float* __restrict__ wnB, const float* __restrict__ wnC,
    const float* __restrict__ Bb, const float* __restrict__ Cb,
    const float* __restrict__ dtb, const float* __restrict__ Alog,
    float* __restrict__ Bn, float* __restrict__ Cn, float* __restrict__ dtth,
    float* __restrict__ dts, float* __restrict__ alphas, float* __restrict__ lams,
    float* __restrict__ xbar, float* Asum)
{
  __shared__ float red[256];
  int r = blockIdx.x, t = threadIdx.x;

  const bf16_t* xr = xbuf + (size_t)r*EDIM;
  bf16x8 xv = *(const bf16x8*)(xr + t*8);
  float s = 0.f;
  #pragma unroll
  for (int i=0;i<8;++i) s += (float)xv[i];
  float xs = blockReduce256(s, red, t);

  const float* zr = zs + (size_t)r*384;
  float dt  = softplus_f(zr[256] + dtb[0]);
  float Av  = -softplus_f(zr[257] + Alog[0]);
  float lam = sigmoid_f(zr[322]);
  float alpha = expf(dt*Av);

  if (t == 0){
    xbar[r]   = xs * (1.f/2048.f);
    dts[r]    = dt;
    alphas[r] = alpha;
    lams[r]   = lam;
    atomicAdd(Asum, Av);
  }
  if (t < 64) dtth[(size_t)r*64 + t] = dt * zr[258+t];

  float bv = (t < 128) ? zr[t]       : 0.f;
  float cv = (t < 128) ? zr[128+t]   : 0.f;
  float b2 = blockReduce256(bv*bv, red, t);
  float c2 = blockReduce256(cv*cv, red, t);
  if (t < 128){
    float rb = rsqrtf(b2*(1.f/128.f) + EPSV);
    float rc = rsqrtf(c2*(1.f/128.f) + EPSV);
    Bn[(size_t)r*128 + t] = bv*rb*wnB[t] + Bb[t];
    Cn[(size_t)r*128 + t] = cv*rc*wnC[t] + Cb[t];
  }
}

// ---------------- kernel 3a: per-chunk angle sums ----------------
__global__ __launch_bounds__(64) void rope_sum_kernel(
    const float* __restrict__ dtth, float* __restrict__ csum)
{
  int b  = blockIdx.x >> 5;
  int ch = blockIdx.x & 31;
  int d  = threadIdx.x;
  const float* base = dtth + ((size_t)b*LSEQ + (size_t)ch*RCLEN)*64 + d;
  float s = 0.f;
  #pragma unroll 4
  for (int i = 0; i < RCLEN; ++i) s += base[(size_t)i*64];
  csum[((size_t)b*RCH + ch)*64 + d] = s;
}

// ---------------- kernel 3b: rope apply with chunk offsets ----------------
__global__ __launch_bounds__(64) void rope_apply_kernel(
    const float* __restrict__ dtth, const float* __restrict__ csum,
    float* __restrict__ Bn, float* __restrict__ Cn)
{
  int b  = blockIdx.x >> 5;
  int ch = blockIdx.x & 31;
  int d  = threadIdx.x;
  float ca = 0.f;
  for (int c = 0; c < ch; ++c) ca += csum[((size_t)b*RCH + c)*64 + d];
  int l0 = ch*RCLEN;
  const float* base = dtth + ((size_t)b*LSEQ)*64 + d;
  for (int l = l0; l < l0 + RCLEN; ++l){
    ca += base[(size_t)l*64];
    float sn, cs;
    sincosf(ca, &sn, &cs);
    size_t ro = ((size_t)b*LSEQ + l)*128;
    float b1 = Bn[ro+d], b2v = Bn[ro+64+d];
    Bn[ro+d]    = b1*cs - b2v*sn;
    Bn[ro+64+d] = b1*sn + b2v*cs;
    float c1 = Cn[ro+d], c2v = Cn[ro+64+d];
    Cn[ro+d]    = c1*cs - c2v*sn;
    Cn[ro+64+d] = c1*sn + c2v*cs;
  }
}

// ---------------- kernel 4a: chunk-local scan ----------------
// block (b,ch): local state scan from 0 over SCLEN tokens; store y_local, P_l,
// chunk-final state, chunk decay product.
__global__ __launch_bounds__(64) void scan_local_kernel(
    const float* __restrict__ dts, const float* __restrict__ alphas,
    const float* __restrict__ lams, const float* __restrict__ xbar,
    const float* __restrict__ Asum,
    const float* __restrict__ Bn, const float* __restrict__ Cn,
    float* __restrict__ ylocal, float* __restrict__ Pfix,
    float* __restrict__ Sfin, float* __restrict__ Dch)
{
  int b  = blockIdx.x / SCHUNK;
  int ch = blockIdx.x % SCHUNK;
  int n  = threadIdx.x;
  float Abar = Asum[0] * (1.f/(float)ROWS);
  float s1 = 0.f, s2 = 0.f, P = 1.f;
  int l0 = ch*SCLEN;
  #pragma unroll
  for (int i = 0; i < SCLEN; ++i){
    int l = l0 + i;
    size_t r = (size_t)b*LSEQ + l;
    float dt = dts[r], lam = lams[r], al = alphas[r], xb = xbar[r];
    float xp = (l > 0) ? xbar[r-1] : 0.f;
    float um = lam*xb + (1.f-lam)*al*xp;
    float dA = expf(dt*Abar);
    float coef = dt*um;
    size_t ro = r*128;
    s1 = dA*s1 + coef*Bn[ro+n];
    s2 = dA*s2 + coef*Bn[ro+64+n];
    P *= dA;
    float p = s1*Cn[ro+n] + s2*Cn[ro+64+n];
    #pragma unroll
    for (int off = 32; off > 0; off >>= 1) p += __shfl_down(p, off);
    if (n == 0){ ylocal[r] = p; Pfix[r] = P; }
  }
  size_t so = ((size_t)b*SCHUNK + ch)*128;
  Sfin[so + n]      = s1;
  Sfin[so + 64 + n] = s2;
  if (n == 0) Dch[b*SCHUNK + ch] = P;
}

// ---------------- kernel 4b: inter-chunk carry ----------------
__global__ __launch_bounds__(128) void scan_carry_kernel(
    const float* __restrict__ Sfin, const float* __restrict__ Dch,
    float* __restrict__ Sin)
{
  int b = blockIdx.x;
  int n = threadIdx.x;   // 0..127
  float s = 0.f;
  for (int c = 0; c < SCHUNK; ++c){
    size_t so = ((size_t)b*SCHUNK + c)*128;
    Sin[so + n] = s;
    s = Dch[b*SCHUNK + c]*s + Sfin[so + n];
  }
}

// ---------------- kernel 4c: fixup  y = y_local + P_l * (C_l . Sin) --------
__global__ __launch_bounds__(256) void scan_fix_kernel(
    const float* __restrict__ Cn, const float* __restrict__ Sin,
    const float* __restrict__ ylocal, const float* __restrict__ Pfix,
    float* __restrict__ outsv)
{
  int r = blockIdx.x*4 + (threadIdx.x>>6);
  int n = threadIdx.x & 63;
  int b  = r / LSEQ;
  int ch = (r % LSEQ) / SCLEN;
  const float* si = Sin + ((size_t)b*SCHUNK + ch)*128;
  size_t ro = (size_t)r*128;
  float p = Cn[ro+n]*si[n] + Cn[ro+64+n]*si[64+n];
  #pragma unroll
  for (int off = 32; off > 0; off >>= 1) p += __shfl_down(p, off);
  if (n == 0) outsv[r] = ylocal[r] + Pfix[r]*p;
}

// ---------------- kernel 5: GEMM2  out = (outs * gate) @ W_out^T ----------------
__global__ __launch_bounds__(256) void gemm2_kernel(
    const bf16_t* __restrict__ A,
    const bf16_t* __restrict__ W,
    const float* __restrict__ outsv,
    float* __restrict__ out)
{
  __shared__ bf16_t lA[128*32];
  __shared__ bf16_t lB[128*32];
  const int K = EDIM;
  int tid = threadIdx.x;
  int wid = tid>>6, lane = tid&63;
  int wr = wid>>1, wc = wid&1;
  int m0 = blockIdx.y*128, n0 = blockIdx.x*128;

  f32x4 acc[4][4] = {};

  int crow = tid>>2;
  int ccol = (tid&3)*8;
  const bf16_t* gA0 = A + (size_t)(m0+crow)*K + ccol;
  const bf16_t* gB0 = W + (size_t)(n0+crow)*K + ccol;

  for (int k0 = 0; k0 < K; k0 += 32){
    gload_lds16(gA0 + k0,        lA + wid*512);
    gload_lds16(gA0 + 64*K + k0, lA + 2048 + wid*512);
    gload_lds16(gB0 + k0,        lB + wid*512);
    gload_lds16(gB0 + 64*K + k0, lB + 2048 + wid*512);
    __syncthreads();
    int lrow = lane&15, lk = (lane>>4)*8;
    bf16x8 af[4], bfr[4];
    #pragma unroll
    for (int m=0;m<4;++m) af[m]  = *(const bf16x8*)&lA[(wr*64+m*16+lrow)*32 + lk];
    #pragma unroll
    for (int n=0;n<4;++n) bfr[n] = *(const bf16x8*)&lB[(wc*64+n*16+lrow)*32 + lk];
    #pragma unroll
    for (int m=0;m<4;++m)
      #pragma unroll
      for (int n=0;n<4;++n)
        acc[m][n] = __builtin_amdgcn_mfma_f32_16x16x32_bf16(af[m], bfr[n], acc[m][n], 0,0,0);
    __syncthreads();
  }

  #pragma unroll
  for (int m=0;m<4;++m){
    int rowb = m0 + wr*64 + m*16 + ((lane>>4)<<2);
    #pragma unroll
    for (int n=0;n<4;++n){
      int col = n0 + wc*64 + n*16 + (lane&15);
      #pragma unroll
      for (int i=0;i<4;++i){
        int r = rowb + i;
        out[(size_t)r*DMODEL + col] = acc[m][n][i] * outsv[r];
      }
    }
  }
}

// ---------------- launch ----------------
extern "C" void kernel_launch(void* const* d_in, const int* in_sizes, int n_in,
                              void* d_out, int out_size, void* d_ws, size_t ws_size,
                              hipStream_t stream)
{
  const float* u    = (const float*)d_in[0];
  const float* W_in = (const float*)d_in[1];
  const float* wnB  = (const float*)d_in[2];
  const float* wnC  = (const float*)d_in[3];
  const float* Bb   = (const float*)d_in[4];
  const float* Cb   = (const float*)d_in[5];
  const float* dtb  = (const float*)d_in[6];
  const float* Alog = (const float*)d_in[7];
  const float* Wout = (const float*)d_in[8];
  float* out = (float*)d_out;
  char* ws = (char*)d_ws;

  constexpr size_t OFF_ASUM = 0;
  constexpr size_t OFF_UBF  = 256;
  constexpr size_t SZ_UBF   = (size_t)ROWS*DMODEL*2;
  constexpr size_t OFF_WIN  = OFF_UBF + SZ_UBF;
  constexpr size_t SZ_WIN   = (size_t)ZPAD*DMODEL*2;
  constexpr size_t OFF_WOUT = OFF_WIN + SZ_WIN;
  constexpr size_t SZ_WOUT  = (size_t)DMODEL*EDIM*2;
  constexpr size_t OFF_X    = OFF_WOUT + SZ_WOUT;
  constexpr size_t SZ_X     = (size_t)ROWS*EDIM*2;
  constexpr size_t OFF_G    = OFF_X + SZ_X;
  constexpr size_t OFF_ZS   = OFF_G + SZ_X;
  constexpr size_t SZ_ZS    = (size_t)ROWS*384*4;
  constexpr size_t OFF_BN   = OFF_ZS + SZ_ZS;
  constexpr size_t SZ_BN    = (size_t)ROWS*128*4;
  constexpr size_t OFF_CN   = OFF_BN + SZ_BN;
  constexpr size_t OFF_DTTH = OFF_CN + SZ_BN;
  constexpr size_t SZ_DTTH  = (size_t)ROWS*64*4;
  constexpr size_t OFF_DT   = OFF_DTTH + SZ_DTTH;
  constexpr size_t OFF_AL   = OFF_DT  + (size_t)ROWS*4;
  constexpr size_t OFF_LAM  = OFF_AL  + (size_t)ROWS*4;
  constexpr size_t OFF_XB   = OFF_LAM + (size_t)ROWS*4;
  constexpr size_t OFF_OUTS = OFF_XB  + (size_t)ROWS*4;
  constexpr size_t OFF_YLOC = OFF_OUTS + (size_t)ROWS*4;
  constexpr size_t OFF_PFIX = OFF_YLOC + (size_t)ROWS*4;
  constexpr size_t OFF_SFIN = OFF_PFIX + (size_t)ROWS*4;
  constexpr size_t SZ_SFIN  = (size_t)B_SZ*SCHUNK*128*4;
  constexpr size_t OFF_DCH  = OFF_SFIN + SZ_SFIN;
  constexpr size_t OFF_SIN  = OFF_DCH + (size_t)B_SZ*SCHUNK*4;
  constexpr size_t OFF_CSUM = OFF_SIN + SZ_SFIN;

  float*  Asum   = (float*) (ws + OFF_ASUM);
  bf16_t* ubf    = (bf16_t*)(ws + OFF_UBF);
  bf16_t* winbf  = (bf16_t*)(ws + OFF_WIN);
  bf16_t* woutbf = (bf16_t*)(ws + OFF_WOUT);
  bf16_t* xbuf   = (bf16_t*)(ws + OFF_X);
  bf16_t* gbuf   = (bf16_t*)(ws + OFF_G);
  float*  zsb    = (float*) (ws + OFF_ZS);
  float*  Bn     = (float*) (ws + OFF_BN);
  float*  Cn     = (float*) (ws + OFF_CN);
  float*  dtth   = (float*) (ws + OFF_DTTH);
  float*  dts    = (float*) (ws + OFF_DT);
  float*  alphas = (float*) (ws + OFF_AL);
  float*  lams   = (float*) (ws + OFF_LAM);
  float*  xbar   = (float*) (ws + OFF_XB);
  float*  outsv  = (float*) (ws + OFF_OUTS);
  float*  ylocal = (float*) (ws + OFF_YLOC);
  float*  Pfix   = (float*) (ws + OFF_PFIX);
  float*  Sfin   = (float*) (ws + OFF_SFIN);
  float*  Dch    = (float*) (ws + OFF_DCH);
  float*  Sin    = (float*) (ws + OFF_SIN);
  float*  csum   = (float*) (ws + OFF_CSUM);

  {
    size_t total = (size_t)ROWS*DMODEL + (size_t)ZPAD*DMODEL + (size_t)DMODEL*EDIM;
    int blocks = (int)((total + 255)/256);
    prep_kernel<<<blocks, 256, 0, stream>>>(u, W_in, Wout, ubf, winbf, woutbf, Asum);
  }
  {
    dim3 g(ZPAD/128, ROWS/128);
    gemm1_kernel<<<g, 256, 0, stream>>>(ubf, winbf, xbuf, gbuf, zsb);
  }
  fuse_kernel<<<ROWS, 256, 0, stream>>>(xbuf, zsb, wnB, wnC, Bb, Cb, dtb, Alog,
                                        Bn, Cn, dtth, dts, alphas, lams, xbar, Asum);
  rope_sum_kernel<<<B_SZ*RCH, 64, 0, stream>>>(dtth, csum);
  rope_apply_kernel<<<B_SZ*RCH, 64, 0, stream>>>(dtth, csum, Bn, Cn);
  scan_local_kernel<<<B_SZ*SCHUNK, 64, 0, stream>>>(dts, alphas, lams, xbar, Asum,
                                                    Bn, Cn, ylocal, Pfix, Sfin, Dch);
  scan_carry_kernel<<<B_SZ, 128, 0, stream>>>(Sfin, Dch, Sin);
  scan_fix_kernel<<<ROWS/4, 256, 0, stream>>>(Cn, Sin, ylocal, Pfix, outsv);
  {
    dim3 g(DMODEL/128, ROWS/128);
    gemm2_kernel<<<g, 256, 0, stream>>>(gbuf, woutbf, outsv, out);
  }
}

// Round 3
// 344.484 us; speedup vs baseline: 5.2574x; 1.2098x over previous
//
#include <hip/hip_runtime.h>
#include <cstdint>
#include <cstddef>

typedef __bf16 bf16_t;
typedef bf16_t bf16x8 __attribute__((ext_vector_type(8)));
typedef float f32x4 __attribute__((ext_vector_type(4)));

#define B_SZ    4
#define LSEQ    2048
#define DMODEL  1024
#define EDIM    2048
#define NSTATE  128
#define ZDIM    4419
#define ZPAD    4608            /* padded to 18 x 256 tiles */
#define ROWS    (B_SZ*LSEQ)     /* 8192 */
#define EPSV    1e-5f

#define SCHUNK  128             /* scan chunks per batch */
#define SCLEN   (LSEQ/SCHUNK)   /* 16 */
#define RCH     128             /* rope chunks per batch */
#define RCLEN   (LSEQ/RCH)      /* 16 */

// ---------------- helpers ----------------
__device__ __forceinline__ float softplus_f(float x){
  return fmaxf(x, 0.f) + log1pf(expf(-fabsf(x)));
}
__device__ __forceinline__ float sigmoid_f(float x){ return 1.f/(1.f+expf(-x)); }
__device__ __forceinline__ float silu_f(float x){ return x/(1.f+expf(-x)); }

__device__ __forceinline__ void gload_lds16(const void* g, void* l){
  __builtin_amdgcn_global_load_lds(
      (const __attribute__((address_space(1))) void*)g,
      (__attribute__((address_space(3))) void*)l, 16, 0, 0);
}

__device__ __forceinline__ float blockReduce256(float v, float* red, int t){
  red[t] = v; __syncthreads();
  #pragma unroll
  for (int off = 128; off > 0; off >>= 1){
    if (t < off) red[t] += red[t+off];
    __syncthreads();
  }
  float r = red[0];
  __syncthreads();
  return r;
}

// ---------------- kernel 0: casts + zero accumulator ----------------
__global__ __launch_bounds__(256) void prep_kernel(
    const float* __restrict__ u, const float* __restrict__ win, const float* __restrict__ wout,
    bf16_t* __restrict__ ubf, bf16_t* __restrict__ winbf, bf16_t* __restrict__ woutbf,
    float* __restrict__ Asum)
{
  size_t i = (size_t)blockIdx.x*256 + threadIdx.x;
  if (i == 0) Asum[0] = 0.f;
  const size_t NU = (size_t)ROWS*DMODEL;
  const size_t NW = (size_t)ZPAD*DMODEL;
  const size_t NO = (size_t)DMODEL*EDIM;
  if (i < NU){ ubf[i] = (bf16_t)u[i]; return; }
  i -= NU;
  if (i < NW){
    size_t n = i >> 10;
    winbf[i] = (n < (size_t)ZDIM) ? (bf16_t)win[i] : (bf16_t)0.f;
    return;
  }
  i -= NW;
  if (i < NO) woutbf[i] = (bf16_t)wout[i];
}

// ---------------- 256-wide 8-wave GEMM template (2-phase, T2 swizzle, T5) ---
// C = A[M][K] @ W[N][K]^T.  BN=256 fixed, BM in {128,256}, BK=64.
// 512 threads = 8 waves, wave grid 2M x 4N, per-wave output (BM/2) x 64.
// LDS: [BM][64] + [BN][64] bf16, chunk-XOR swizzle (16B chunk ^= row&7),
// applied on pre-swizzled global_load_lds SOURCE and on the ds_read address.
// MODE 0: GEMM1 epilogue (silu->xbuf / silu->gbuf / zs split)
// MODE 1: GEMM2 epilogue (row-scale by outsv -> out fp32)
template<int BM, int KDIM, int MODE>
__global__ __launch_bounds__(512, 2) void gemm8_kernel(
    const bf16_t* __restrict__ A, const bf16_t* __restrict__ W,
    bf16_t* __restrict__ o_x, bf16_t* __restrict__ o_g, float* __restrict__ o_z,
    const float* __restrict__ scale, float* __restrict__ o_f)
{
  constexpr int BN  = 256;
  constexpr int NT  = KDIM/64;
  constexpr int MR  = BM/32;            // M fragments per wave
  constexpr int BUFE = (BM+BN)*64;      // elements per buffer
  __shared__ __align__(16) bf16_t lds[BUFE*2];

  const int tid  = threadIdx.x;
  const int wid  = tid>>6, lane = tid&63;
  const int wr   = wid>>2, wc = wid&3;
  const int m0   = blockIdx.y*BM, n0 = blockIdx.x*BN;
  const int lr   = lane&15;

  f32x4 acc[MR][4] = {};

  // stage K-tile t into buffer buf
  auto stage = [&](int buf, int t){
    bf16_t* lA = lds + buf*BUFE;
    bf16_t* lB = lA + BM*64;
    const int k0 = t*64;
    #pragma unroll
    for (int q = 0; q < BM/64; ++q){
      int cidx = q*512 + tid;
      int row = cidx>>3, sc = (cidx&7) ^ (row&7);
      gload_lds16(A + (size_t)(m0+row)*KDIM + k0 + sc*8,
                  lA + (size_t)(q*512 + wid*64)*8);
    }
    #pragma unroll
    for (int q = 0; q < BN/64; ++q){
      int cidx = q*512 + tid;
      int row = cidx>>3, sc = (cidx&7) ^ (row&7);
      gload_lds16(W + (size_t)(n0+row)*KDIM + k0 + sc*8,
                  lB + (size_t)(q*512 + wid*64)*8);
    }
  };

  stage(0, 0);
  __syncthreads();
  int cur = 0;
  for (int t = 0; t < NT; ++t){
    if (t+1 < NT) stage(cur^1, t+1);
    const bf16_t* lA = lds + cur*BUFE;
    const bf16_t* lB = lA + BM*64;
    #pragma unroll
    for (int kk = 0; kk < 2; ++kk){
      const int g = kk*4 + (lane>>4);
      bf16x8 bfr[4], af[MR];
      #pragma unroll
      for (int n = 0; n < 4; ++n){
        int rr = wc*64 + n*16 + lr;
        bfr[n] = *(const bf16x8*)&lB[rr*64 + ((g^(rr&7))<<3)];
      }
      #pragma unroll
      for (int m = 0; m < MR; ++m){
        int rr = wr*(BM/2) + m*16 + lr;
        af[m] = *(const bf16x8*)&lA[rr*64 + ((g^(rr&7))<<3)];
      }
      __builtin_amdgcn_s_setprio(1);
      #pragma unroll
      for (int m = 0; m < MR; ++m)
        #pragma unroll
        for (int n = 0; n < 4; ++n)
          acc[m][n] = __builtin_amdgcn_mfma_f32_16x16x32_bf16(af[m], bfr[n], acc[m][n], 0,0,0);
      __builtin_amdgcn_s_setprio(0);
    }
    __syncthreads();   // drains vmcnt (staged loads) + lgkmcnt
    cur ^= 1;
  }

  // epilogue
  #pragma unroll
  for (int m = 0; m < MR; ++m){
    int rowb = m0 + wr*(BM/2) + m*16 + ((lane>>4)<<2);
    #pragma unroll
    for (int n = 0; n < 4; ++n){
      int col = n0 + wc*64 + n*16 + lr;
      #pragma unroll
      for (int i = 0; i < 4; ++i){
        int r = rowb + i;
        float v = acc[m][n][i];
        if (MODE == 0){
          if (col < 2048)       o_x[(size_t)r*EDIM + col]        = (bf16_t)silu_f(v);
          else if (col < 4096)  o_g[(size_t)r*EDIM + (col-2048)] = (bf16_t)silu_f(v);
          else if (col < 4480)  o_z[(size_t)r*384 + (col-4096)]  = v;
        } else {
          o_f[(size_t)r*DMODEL + col] = v * scale[r];
        }
      }
    }
  }
}

// ---------------- kernel 2: per-token fuse ----------------
__global__ __launch_bounds__(256) void fuse_kernel(
    const bf16_t* __restrict__ xbuf, const float* __restrict__ zs,
    const float* __restrict__ wnB, const float* __restrict__ wnC,
    const float* __restrict__ Bb, const float* __restrict__ Cb,
    const float* __restrict__ dtb, const float* __restrict__ Alog,
    float* __restrict__ Bn, float* __restrict__ Cn, float* __restrict__ dtth,
    float* __restrict__ dts, float* __restrict__ alphas, float* __restrict__ lams,
    float* __restrict__ xbar, float* Asum)
{
  __shared__ float red[256];
  int r = blockIdx.x, t = threadIdx.x;

  const bf16_t* xr = xbuf + (size_t)r*EDIM;
  bf16x8 xv = *(const bf16x8*)(xr + t*8);
  float s = 0.f;
  #pragma unroll
  for (int i=0;i<8;++i) s += (float)xv[i];
  float xs = blockReduce256(s, red, t);

  const float* zr = zs + (size_t)r*384;
  float dt  = softplus_f(zr[256] + dtb[0]);
  float Av  = -softplus_f(zr[257] + Alog[0]);
  float lam = sigmoid_f(zr[322]);
  float alpha = expf(dt*Av);

  if (t == 0){
    xbar[r]   = xs * (1.f/2048.f);
    dts[r]    = dt;
    alphas[r] = alpha;
    lams[r]   = lam;
    atomicAdd(Asum, Av);
  }
  if (t < 64) dtth[(size_t)r*64 + t] = dt * zr[258+t];

  float bv = (t < 128) ? zr[t]       : 0.f;
  float cv = (t < 128) ? zr[128+t]   : 0.f;
  float b2 = blockReduce256(bv*bv, red, t);
  float c2 = blockReduce256(cv*cv, red, t);
  if (t < 128){
    float rb = rsqrtf(b2*(1.f/128.f) + EPSV);
    float rc = rsqrtf(c2*(1.f/128.f) + EPSV);
    Bn[(size_t)r*128 + t] = bv*rb*wnB[t] + Bb[t];
    Cn[(size_t)r*128 + t] = cv*rc*wnC[t] + Cb[t];
  }
}

// ---------------- kernel 3a: per-chunk angle sums ----------------
__global__ __launch_bounds__(64) void rope_sum_kernel(
    const float* __restrict__ dtth, float* __restrict__ csum)
{
  int b  = blockIdx.x >> 7;
  int ch = blockIdx.x & 127;
  int d  = threadIdx.x;
  const float* base = dtth + ((size_t)b*LSEQ + (size_t)ch*RCLEN)*64 + d;
  float s = 0.f;
  #pragma unroll
  for (int i = 0; i < RCLEN; ++i) s += base[(size_t)i*64];
  csum[((size_t)b*RCH + ch)*64 + d] = s;
}

// ---------------- kernel 3b: exclusive prefix over chunks (in place) -------
__global__ __launch_bounds__(64) void rope_prefix_kernel(float* __restrict__ csum)
{
  int b = blockIdx.x, d = threadIdx.x;
  float s = 0.f;
  for (int c = 0; c < RCH; ++c){
    size_t idx = ((size_t)b*RCH + c)*64 + d;
    float v = csum[idx]; csum[idx] = s; s += v;
  }
}

// ---------------- kernel 3c: rope apply with chunk offsets ----------------
__global__ __launch_bounds__(64) void rope_apply_kernel(
    const float* __restrict__ dtth, const float* __restrict__ csum,
    float* __restrict__ Bn, float* __restrict__ Cn)
{
  int b  = blockIdx.x >> 7;
  int ch = blockIdx.x & 127;
  int d  = threadIdx.x;
  float ca = csum[((size_t)b*RCH + ch)*64 + d];
  int l0 = ch*RCLEN;
  const float* base = dtth + ((size_t)b*LSEQ)*64 + d;
  for (int l = l0; l < l0 + RCLEN; ++l){
    ca += base[(size_t)l*64];
    float sn, cs;
    sincosf(ca, &sn, &cs);
    size_t ro = ((size_t)b*LSEQ + l)*128;
    float b1 = Bn[ro+d], b2v = Bn[ro+64+d];
    Bn[ro+d]    = b1*cs - b2v*sn;
    Bn[ro+64+d] = b1*sn + b2v*cs;
    float c1 = Cn[ro+d], c2v = Cn[ro+64+d];
    Cn[ro+d]    = c1*cs - c2v*sn;
    Cn[ro+64+d] = c1*sn + c2v*cs;
  }
}

// ---------------- kernel 4a: chunk-local scan ----------------
__global__ __launch_bounds__(64) void scan_local_kernel(
    const float* __restrict__ dts, const float* __restrict__ alphas,
    const float* __restrict__ lams, const float* __restrict__ xbar,
    const float* __restrict__ Asum,
    const float* __restrict__ Bn, const float* __restrict__ Cn,
    float* __restrict__ ylocal, float* __restrict__ Pfix,
    float* __restrict__ Sfin, float* __restrict__ Dch)
{
  int b  = blockIdx.x / SCHUNK;
  int ch = blockIdx.x % SCHUNK;
  int n  = threadIdx.x;
  float Abar = Asum[0] * (1.f/(float)ROWS);
  float s1 = 0.f, s2 = 0.f, P = 1.f;
  int l0 = ch*SCLEN;
  #pragma unroll
  for (int i = 0; i < SCLEN; ++i){
    int l = l0 + i;
    size_t r = (size_t)b*LSEQ + l;
    float dt = dts[r], lam = lams[r], al = alphas[r], xb = xbar[r];
    float xp = (l > 0) ? xbar[r-1] : 0.f;
    float um = lam*xb + (1.f-lam)*al*xp;
    float dA = expf(dt*Abar);
    float coef = dt*um;
    size_t ro = r*128;
    s1 = dA*s1 + coef*Bn[ro+n];
    s2 = dA*s2 + coef*Bn[ro+64+n];
    P *= dA;
    float p = s1*Cn[ro+n] + s2*Cn[ro+64+n];
    #pragma unroll
    for (int off = 32; off > 0; off >>= 1) p += __shfl_down(p, off);
    if (n == 0){ ylocal[r] = p; Pfix[r] = P; }
  }
  size_t so = ((size_t)b*SCHUNK + ch)*128;
  Sfin[so + n]      = s1;
  Sfin[so + 64 + n] = s2;
  if (n == 0) Dch[b*SCHUNK + ch] = P;
}

// ---------------- kernel 4b: inter-chunk carry ----------------
__global__ __launch_bounds__(128) void scan_carry_kernel(
    const float* __restrict__ Sfin, const float* __restrict__ Dch,
    float* __restrict__ Sin)
{
  int b = blockIdx.x;
  int n = threadIdx.x;   // 0..127
  float s = 0.f;
  for (int c = 0; c < SCHUNK; ++c){
    size_t so = ((size_t)b*SCHUNK + c)*128;
    Sin[so + n] = s;
    s = Dch[b*SCHUNK + c]*s + Sfin[so + n];
  }
}

// ---------------- kernel 4c: fixup  y = y_local + P_l * (C_l . Sin) --------
__global__ __launch_bounds__(256) void scan_fix_kernel(
    const float* __restrict__ Cn, const float* __restrict__ Sin,
    const float* __restrict__ ylocal, const float* __restrict__ Pfix,
    float* __restrict__ outsv)
{
  int r = blockIdx.x*4 + (threadIdx.x>>6);
  int n = threadIdx.x & 63;
  int b  = r / LSEQ;
  int ch = (r % LSEQ) / SCLEN;
  const float* si = Sin + ((size_t)b*SCHUNK + ch)*128;
  size_t ro = (size_t)r*128;
  float p = Cn[ro+n]*si[n] + Cn[ro+64+n]*si[64+n];
  #pragma unroll
  for (int off = 32; off > 0; off >>= 1) p += __shfl_down(p, off);
  if (n == 0) outsv[r] = ylocal[r] + Pfix[r]*p;
}

// ---------------- launch ----------------
extern "C" void kernel_launch(void* const* d_in, const int* in_sizes, int n_in,
                              void* d_out, int out_size, void* d_ws, size_t ws_size,
                              hipStream_t stream)
{
  const float* u    = (const float*)d_in[0];
  const float* W_in = (const float*)d_in[1];
  const float* wnB  = (const float*)d_in[2];
  const float* wnC  = (const float*)d_in[3];
  const float* Bb   = (const float*)d_in[4];
  const float* Cb   = (const float*)d_in[5];
  const float* dtb  = (const float*)d_in[6];
  const float* Alog = (const float*)d_in[7];
  const float* Wout = (const float*)d_in[8];
  float* out = (float*)d_out;
  char* ws = (char*)d_ws;

  constexpr size_t OFF_ASUM = 0;
  constexpr size_t OFF_UBF  = 256;
  constexpr size_t SZ_UBF   = (size_t)ROWS*DMODEL*2;
  constexpr size_t OFF_WIN  = OFF_UBF + SZ_UBF;
  constexpr size_t SZ_WIN   = (size_t)ZPAD*DMODEL*2;
  constexpr size_t OFF_WOUT = OFF_WIN + SZ_WIN;
  constexpr size_t SZ_WOUT  = (size_t)DMODEL*EDIM*2;
  constexpr size_t OFF_X    = OFF_WOUT + SZ_WOUT;
  constexpr size_t SZ_X     = (size_t)ROWS*EDIM*2;
  constexpr size_t OFF_G    = OFF_X + SZ_X;
  constexpr size_t OFF_ZS   = OFF_G + SZ_X;
  constexpr size_t SZ_ZS    = (size_t)ROWS*384*4;
  constexpr size_t OFF_BN   = OFF_ZS + SZ_ZS;
  constexpr size_t SZ_BN    = (size_t)ROWS*128*4;
  constexpr size_t OFF_CN   = OFF_BN + SZ_BN;
  constexpr size_t OFF_DTTH = OFF_CN + SZ_BN;
  constexpr size_t SZ_DTTH  = (size_t)ROWS*64*4;
  constexpr size_t OFF_DT   = OFF_DTTH + SZ_DTTH;
  constexpr size_t OFF_AL   = OFF_DT  + (size_t)ROWS*4;
  constexpr size_t OFF_LAM  = OFF_AL  + (size_t)ROWS*4;
  constexpr size_t OFF_XB   = OFF_LAM + (size_t)ROWS*4;
  constexpr size_t OFF_OUTS = OFF_XB  + (size_t)ROWS*4;
  constexpr size_t OFF_YLOC = OFF_OUTS + (size_t)ROWS*4;
  constexpr size_t OFF_PFIX = OFF_YLOC + (size_t)ROWS*4;
  constexpr size_t OFF_SFIN = OFF_PFIX + (size_t)ROWS*4;
  constexpr size_t SZ_SFIN  = (size_t)B_SZ*SCHUNK*128*4;
  constexpr size_t OFF_DCH  = OFF_SFIN + SZ_SFIN;
  constexpr size_t OFF_SIN  = OFF_DCH + (size_t)B_SZ*SCHUNK*4;
  constexpr size_t OFF_CSUM = OFF_SIN + SZ_SFIN;

  float*  Asum   = (float*) (ws + OFF_ASUM);
  bf16_t* ubf    = (bf16_t*)(ws + OFF_UBF);
  bf16_t* winbf  = (bf16_t*)(ws + OFF_WIN);
  bf16_t* woutbf = (bf16_t*)(ws + OFF_WOUT);
  bf16_t* xbuf   = (bf16_t*)(ws + OFF_X);
  bf16_t* gbuf   = (bf16_t*)(ws + OFF_G);
  float*  zsb    = (float*) (ws + OFF_ZS);
  float*  Bn     = (float*) (ws + OFF_BN);
  float*  Cn     = (float*) (ws + OFF_CN);
  float*  dtth   = (float*) (ws + OFF_DTTH);
  float*  dts    = (float*) (ws + OFF_DT);
  float*  alphas = (float*) (ws + OFF_AL);
  float*  lams   = (float*) (ws + OFF_LAM);
  float*  xbar   = (float*) (ws + OFF_XB);
  float*  outsv  = (float*) (ws + OFF_OUTS);
  float*  ylocal = (float*) (ws + OFF_YLOC);
  float*  Pfix   = (float*) (ws + OFF_PFIX);
  float*  Sfin   = (float*) (ws + OFF_SFIN);
  float*  Dch    = (float*) (ws + OFF_DCH);
  float*  Sin    = (float*) (ws + OFF_SIN);
  float*  csum   = (float*) (ws + OFF_CSUM);

  {
    size_t total = (size_t)ROWS*DMODEL + (size_t)ZPAD*DMODEL + (size_t)DMODEL*EDIM;
    int blocks = (int)((total + 255)/256);
    prep_kernel<<<blocks, 256, 0, stream>>>(u, W_in, Wout, ubf, winbf, woutbf, Asum);
  }
  {
    dim3 g(ZPAD/256, ROWS/256);   // 18 x 32
    gemm8_kernel<256, DMODEL, 0><<<g, 512, 0, stream>>>(
        ubf, winbf, xbuf, gbuf, zsb, nullptr, nullptr);
  }
  fuse_kernel<<<ROWS, 256, 0, stream>>>(xbuf, zsb, wnB, wnC, Bb, Cb, dtb, Alog,
                                        Bn, Cn, dtth, dts, alphas, lams, xbar, Asum);
  rope_sum_kernel<<<B_SZ*RCH, 64, 0, stream>>>(dtth, csum);
  rope_prefix_kernel<<<B_SZ, 64, 0, stream>>>(csum);
  rope_apply_kernel<<<B_SZ*RCH, 64, 0, stream>>>(dtth, csum, Bn, Cn);
  scan_local_kernel<<<B_SZ*SCHUNK, 64, 0, stream>>>(dts, alphas, lams, xbar, Asum,
                                                    Bn, Cn, ylocal, Pfix, Sfin, Dch);
  scan_carry_kernel<<<B_SZ, 128, 0, stream>>>(Sfin, Dch, Sin);
  scan_fix_kernel<<<ROWS/4, 256, 0, stream>>>(Cn, Sin, ylocal, Pfix, outsv);
  {
    dim3 g(DMODEL/256, ROWS/128);  // 4 x 64 = 256 blocks
    gemm8_kernel<128, EDIM, 1><<<g, 512, 0, stream>>>(
        gbuf, woutbf, nullptr, nullptr, nullptr, outsv, out);
  }
}

// Round 4
// 338.046 us; speedup vs baseline: 5.3576x; 1.0190x over previous
//
#include <hip/hip_runtime.h>
#include <cstdint>
#include <cstddef>

typedef __bf16 bf16_t;
typedef bf16_t bf16x8 __attribute__((ext_vector_type(8)));
typedef float f32x4 __attribute__((ext_vector_type(4)));

#define B_SZ    4
#define LSEQ    2048
#define DMODEL  1024
#define EDIM    2048
#define ZDIM    4419
#define ZPAD    4608            /* padded to 18 x 256 tiles */
#define ROWS    (B_SZ*LSEQ)     /* 8192 */
#define EPSV    1e-5f

#define SCHUNK  128             /* scan chunks per batch */
#define SCLEN   (LSEQ/SCHUNK)   /* 16 */
#define RCH     128             /* rope chunks per batch */
#define RCLEN   (LSEQ/RCH)      /* 16 */

// ---------------- helpers ----------------
__device__ __forceinline__ float softplus_f(float x){
  return fmaxf(x, 0.f) + log1pf(expf(-fabsf(x)));
}
__device__ __forceinline__ float sigmoid_f(float x){ return 1.f/(1.f+expf(-x)); }
__device__ __forceinline__ float silu_f(float x){ return x/(1.f+expf(-x)); }

__device__ __forceinline__ void gload_lds16(const void* g, void* l){
  __builtin_amdgcn_global_load_lds(
      (const __attribute__((address_space(1))) void*)g,
      (__attribute__((address_space(3))) void*)l, 16, 0, 0);
}

__device__ __forceinline__ float blockReduce128(float v, float* red, int t){
  red[t] = v; __syncthreads();
  #pragma unroll
  for (int off = 64; off > 0; off >>= 1){
    if (t < off) red[t] += red[t+off];
    __syncthreads();
  }
  float r = red[0];
  __syncthreads();
  return r;
}

// ---------------- kernel 0: casts + zero accumulators ----------------
__global__ __launch_bounds__(256) void prep_kernel(
    const float* __restrict__ u, const float* __restrict__ win, const float* __restrict__ wout,
    bf16_t* __restrict__ ubf, bf16_t* __restrict__ winbf, bf16_t* __restrict__ woutbf,
    float* __restrict__ Asum, float* __restrict__ xraw)
{
  size_t i = (size_t)blockIdx.x*256 + threadIdx.x;
  if (i == 0) Asum[0] = 0.f;
  if (i < ROWS) xraw[i] = 0.f;
  const size_t NU = (size_t)ROWS*DMODEL;
  const size_t NW = (size_t)ZPAD*DMODEL;
  const size_t NO = (size_t)DMODEL*EDIM;
  if (i < NU){ ubf[i] = (bf16_t)u[i]; return; }
  i -= NU;
  if (i < NW){
    size_t n = i >> 10;
    winbf[i] = (n < (size_t)ZDIM) ? (bf16_t)win[i] : (bf16_t)0.f;
    return;
  }
  i -= NW;
  if (i < NO) woutbf[i] = (bf16_t)wout[i];
}

// ---------------- deep-pipelined GEMM (T1+T2+T4+T5) ----------------
// C = A[M][K] @ W[N][K]^T.  BN=256, BM=128, BK=64, 512 thr = 8 waves (2M x 4N),
// per-wave 64x64 output. 3 LDS buffers (144 KB), depth-2 prefetch, counted
// vmcnt (12 steady / 6 / 0 tail), raw s_barrier (no drain), T2 chunk-XOR
// swizzle on both sides, setprio around MFMA cluster, bijective XCD swizzle.
// MODE 0 (GEMM1): x-region -> silu row-sum atomics into xraw (no store);
//                 gate-region -> silu -> o_g bf16; z-region -> o_z fp32.
// MODE 1 (GEMM2): out = acc * scale[row] -> o_f fp32.
template<int BM, int KDIM, int NXT, int MODE>
__global__ __launch_bounds__(512, 2) void gemmDP_kernel(
    const bf16_t* __restrict__ A, const bf16_t* __restrict__ W,
    float* __restrict__ xraw, bf16_t* __restrict__ o_g, float* __restrict__ o_z,
    const float* __restrict__ scale, float* __restrict__ o_f)
{
  constexpr int BN = 256;
  constexpr int NT = KDIM/64;
  constexpr int MR = BM/32;
  constexpr int BUFE = (BM+BN)*64;
  __shared__ __align__(16) bf16_t lds[BUFE*3];

  const int tid = threadIdx.x;
  const int wid = tid>>6, lane = tid&63;
  const int wr = wid>>2, wc = wid&3;
  const int lr = lane&15;

  const int nwg = NXT*(ROWS/BM);
  const int id = blockIdx.x;
  const int rid = (id & 7)*(nwg>>3) + (id>>3);   // bijective: nwg % 8 == 0
  const int bx = rid % NXT, by = rid / NXT;
  const int m0 = by*BM, n0 = bx*BN;

  f32x4 acc[MR][4] = {};

  auto stage = [&](int buf, int t){
    bf16_t* lA = lds + buf*BUFE;
    bf16_t* lB = lA + BM*64;
    const int k0 = t*64;
    #pragma unroll
    for (int q = 0; q < BM/64; ++q){
      int cidx = q*512 + tid;
      int row = cidx>>3, sc = (cidx&7) ^ (row&7);
      gload_lds16(A + (size_t)(m0+row)*KDIM + k0 + sc*8,
                  lA + (size_t)(q*512 + wid*64)*8);
    }
    #pragma unroll
    for (int q = 0; q < BN/64; ++q){
      int cidx = q*512 + tid;
      int row = cidx>>3, sc = (cidx&7) ^ (row&7);
      gload_lds16(W + (size_t)(n0+row)*KDIM + k0 + sc*8,
                  lB + (size_t)(q*512 + wid*64)*8);
    }
  };

  auto compute = [&](int buf){
    const bf16_t* lA = lds + buf*BUFE;
    const bf16_t* lB = lA + BM*64;
    #pragma unroll
    for (int kk = 0; kk < 2; ++kk){
      const int g = kk*4 + (lane>>4);
      bf16x8 bfr[4], af[MR];
      #pragma unroll
      for (int n = 0; n < 4; ++n){
        int rr = wc*64 + n*16 + lr;
        bfr[n] = *(const bf16x8*)&lB[rr*64 + ((g^(rr&7))<<3)];
      }
      #pragma unroll
      for (int m = 0; m < MR; ++m){
        int rr = wr*(BM/2) + m*16 + lr;
        af[m] = *(const bf16x8*)&lA[rr*64 + ((g^(rr&7))<<3)];
      }
      __builtin_amdgcn_s_setprio(1);
      #pragma unroll
      for (int m = 0; m < MR; ++m)
        #pragma unroll
        for (int n = 0; n < 4; ++n)
          acc[m][n] = __builtin_amdgcn_mfma_f32_16x16x32_bf16(af[m], bfr[n], acc[m][n], 0,0,0);
      __builtin_amdgcn_s_setprio(0);
    }
  };

  stage(0, 0);
  stage(1, 1);
  int cur = 0;
  for (int t = 0; t + 2 < NT; ++t){
    int nb = cur + 2; if (nb >= 3) nb -= 3;
    stage(nb, t+2);
    asm volatile("s_waitcnt vmcnt(12)" ::: "memory");  // tile t landed; t+1,t+2 in flight
    asm volatile("s_barrier" ::: "memory");
    compute(cur);
    asm volatile("s_barrier" ::: "memory");
    if (++cur == 3) cur = 0;
  }
  asm volatile("s_waitcnt vmcnt(6)" ::: "memory");
  asm volatile("s_barrier" ::: "memory");
  compute(cur);
  asm volatile("s_barrier" ::: "memory");
  if (++cur == 3) cur = 0;
  asm volatile("s_waitcnt vmcnt(0)" ::: "memory");
  asm volatile("s_barrier" ::: "memory");
  compute(cur);

  // ---- epilogue (branch is uniform per block: region boundaries are 256-aligned)
  if (MODE == 0 && n0 < 2048){
    // x region: only the per-row silu mean is ever needed downstream
    #pragma unroll
    for (int m = 0; m < MR; ++m){
      #pragma unroll
      for (int i = 0; i < 4; ++i){
        float p = 0.f;
        #pragma unroll
        for (int n = 0; n < 4; ++n) p += silu_f(acc[m][n][i]);
        #pragma unroll
        for (int off = 8; off > 0; off >>= 1) p += __shfl_xor(p, off);
        if (lr == 0){
          int r = m0 + wr*(BM/2) + m*16 + ((lane>>4)<<2) + i;
          atomicAdd(xraw + r, p);
        }
      }
    }
  } else {
    #pragma unroll
    for (int m = 0; m < MR; ++m){
      int rowb = m0 + wr*(BM/2) + m*16 + ((lane>>4)<<2);
      #pragma unroll
      for (int n = 0; n < 4; ++n){
        int col = n0 + wc*64 + n*16 + lr;
        #pragma unroll
        for (int i = 0; i < 4; ++i){
          int r = rowb + i;
          float v = acc[m][n][i];
          if (MODE == 0){
            if (col < 4096)      o_g[(size_t)r*EDIM + (col-2048)] = (bf16_t)silu_f(v);
            else if (col < 4480) o_z[(size_t)r*384 + (col-4096)]  = v;
          } else {
            o_f[(size_t)r*DMODEL + col] = v * scale[r];
          }
        }
      }
    }
  }
}

// ---------------- kernel 2: per-token fuse (RMS + scalars) ----------------
__global__ __launch_bounds__(128) void fuse_kernel(
    const float* __restrict__ xraw, const float* __restrict__ zs,
    const float* __restrict__ wnB, const float* __restrict__ wnC,
    const float* __restrict__ Bb, const float* __restrict__ Cb,
    const float* __restrict__ dtb, const float* __restrict__ Alog,
    float* __restrict__ Bn, float* __restrict__ Cn, float* __restrict__ dtth,
    float* __restrict__ dts, float* __restrict__ alphas, float* __restrict__ lams,
    float* __restrict__ xbar, float* Asum)
{
  __shared__ float red[128];
  int r = blockIdx.x, t = threadIdx.x;
  const float* zr = zs + (size_t)r*384;
  float bv = zr[t], cv = zr[128+t];
  float b2 = blockReduce128(bv*bv, red, t);
  float c2 = blockReduce128(cv*cv, red, t);
  float rb = rsqrtf(b2*(1.f/128.f) + EPSV);
  float rc = rsqrtf(c2*(1.f/128.f) + EPSV);
  Bn[(size_t)r*128 + t] = bv*rb*wnB[t] + Bb[t];
  Cn[(size_t)r*128 + t] = cv*rc*wnC[t] + Cb[t];

  float dt = softplus_f(zr[256] + dtb[0]);
  if (t < 64) dtth[(size_t)r*64 + t] = dt * zr[258+t];
  if (t == 0){
    float Av  = -softplus_f(zr[257] + Alog[0]);
    float lam = sigmoid_f(zr[322]);
    dts[r]    = dt;
    alphas[r] = expf(dt*Av);
    lams[r]   = lam;
    xbar[r]   = xraw[r] * (1.f/2048.f);
    atomicAdd(Asum, Av);
  }
}

// ---------------- kernel 3a: per-chunk angle sums ----------------
__global__ __launch_bounds__(64) void rope_sum_kernel(
    const float* __restrict__ dtth, float* __restrict__ csum)
{
  int b  = blockIdx.x >> 7;
  int ch = blockIdx.x & 127;
  int d  = threadIdx.x;
  const float* base = dtth + ((size_t)b*LSEQ + (size_t)ch*RCLEN)*64 + d;
  float s = 0.f;
  #pragma unroll
  for (int i = 0; i < RCLEN; ++i) s += base[(size_t)i*64];
  csum[((size_t)b*RCH + ch)*64 + d] = s;
}

// ---------------- kernel 3b: exclusive prefix over chunks (in place) -------
__global__ __launch_bounds__(64) void rope_prefix_kernel(float* __restrict__ csum)
{
  int b = blockIdx.x, d = threadIdx.x;
  float s = 0.f;
  for (int c = 0; c < RCH; ++c){
    size_t idx = ((size_t)b*RCH + c)*64 + d;
    float v = csum[idx]; csum[idx] = s; s += v;
  }
}

// ---------------- kernel 3c: rope apply with chunk offsets ----------------
__global__ __launch_bounds__(64) void rope_apply_kernel(
    const float* __restrict__ dtth, const float* __restrict__ csum,
    float* __restrict__ Bn, float* __restrict__ Cn)
{
  int b  = blockIdx.x >> 7;
  int ch = blockIdx.x & 127;
  int d  = threadIdx.x;
  float ca = csum[((size_t)b*RCH + ch)*64 + d];
  int l0 = ch*RCLEN;
  const float* base = dtth + ((size_t)b*LSEQ)*64 + d;
  for (int l = l0; l < l0 + RCLEN; ++l){
    ca += base[(size_t)l*64];
    float sn, cs;
    sincosf(ca, &sn, &cs);
    size_t ro = ((size_t)b*LSEQ + l)*128;
    float b1 = Bn[ro+d], b2v = Bn[ro+64+d];
    Bn[ro+d]    = b1*cs - b2v*sn;
    Bn[ro+64+d] = b1*sn + b2v*cs;
    float c1 = Cn[ro+d], c2v = Cn[ro+64+d];
    Cn[ro+d]    = c1*cs - c2v*sn;
    Cn[ro+64+d] = c1*sn + c2v*cs;
  }
}

// ---------------- kernel 4a: chunk-local scan ----------------
__global__ __launch_bounds__(64) void scan_local_kernel(
    const float* __restrict__ dts, const float* __restrict__ alphas,
    const float* __restrict__ lams, const float* __restrict__ xbar,
    const float* __restrict__ Asum,
    const float* __restrict__ Bn, const float* __restrict__ Cn,
    float* __restrict__ ylocal, float* __restrict__ Pfix,
    float* __restrict__ Sfin, float* __restrict__ Dch)
{
  int b  = blockIdx.x / SCHUNK;
  int ch = blockIdx.x % SCHUNK;
  int n  = threadIdx.x;
  float Abar = Asum[0] * (1.f/(float)ROWS);
  float s1 = 0.f, s2 = 0.f, P = 1.f;
  int l0 = ch*SCLEN;
  #pragma unroll
  for (int i = 0; i < SCLEN; ++i){
    int l = l0 + i;
    size_t r = (size_t)b*LSEQ + l;
    float dt = dts[r], lam = lams[r], al = alphas[r], xb = xbar[r];
    float xp = (l > 0) ? xbar[r-1] : 0.f;
    float um = lam*xb + (1.f-lam)*al*xp;
    float dA = expf(dt*Abar);
    float coef = dt*um;
    size_t ro = r*128;
    s1 = dA*s1 + coef*Bn[ro+n];
    s2 = dA*s2 + coef*Bn[ro+64+n];
    P *= dA;
    float p = s1*Cn[ro+n] + s2*Cn[ro+64+n];
    #pragma unroll
    for (int off = 32; off > 0; off >>= 1) p += __shfl_down(p, off);
    if (n == 0){ ylocal[r] = p; Pfix[r] = P; }
  }
  size_t so = ((size_t)b*SCHUNK + ch)*128;
  Sfin[so + n]      = s1;
  Sfin[so + 64 + n] = s2;
  if (n == 0) Dch[b*SCHUNK + ch] = P;
}

// ---------------- kernel 4b: inter-chunk carry ----------------
__global__ __launch_bounds__(128) void scan_carry_kernel(
    const float* __restrict__ Sfin, const float* __restrict__ Dch,
    float* __restrict__ Sin)
{
  int b = blockIdx.x;
  int n = threadIdx.x;   // 0..127
  float s = 0.f;
  for (int c = 0; c < SCHUNK; ++c){
    size_t so = ((size_t)b*SCHUNK + c)*128;
    Sin[so + n] = s;
    s = Dch[b*SCHUNK + c]*s + Sfin[so + n];
  }
}

// ---------------- kernel 4c: fixup  y = y_local + P_l * (C_l . Sin) --------
__global__ __launch_bounds__(256) void scan_fix_kernel(
    const float* __restrict__ Cn, const float* __restrict__ Sin,
    const float* __restrict__ ylocal, const float* __restrict__ Pfix,
    float* __restrict__ outsv)
{
  int r = blockIdx.x*4 + (threadIdx.x>>6);
  int n = threadIdx.x & 63;
  int b  = r / LSEQ;
  int ch = (r % LSEQ) / SCLEN;
  const float* si = Sin + ((size_t)b*SCHUNK + ch)*128;
  size_t ro = (size_t)r*128;
  float p = Cn[ro+n]*si[n] + Cn[ro+64+n]*si[64+n];
  #pragma unroll
  for (int off = 32; off > 0; off >>= 1) p += __shfl_down(p, off);
  if (n == 0) outsv[r] = ylocal[r] + Pfix[r]*p;
}

// ---------------- launch ----------------
extern "C" void kernel_launch(void* const* d_in, const int* in_sizes, int n_in,
                              void* d_out, int out_size, void* d_ws, size_t ws_size,
                              hipStream_t stream)
{
  const float* u    = (const float*)d_in[0];
  const float* W_in = (const float*)d_in[1];
  const float* wnB  = (const float*)d_in[2];
  const float* wnC  = (const float*)d_in[3];
  const float* Bb   = (const float*)d_in[4];
  const float* Cb   = (const float*)d_in[5];
  const float* dtb  = (const float*)d_in[6];
  const float* Alog = (const float*)d_in[7];
  const float* Wout = (const float*)d_in[8];
  float* out = (float*)d_out;
  char* ws = (char*)d_ws;

  constexpr size_t OFF_ASUM = 0;
  constexpr size_t OFF_UBF  = 256;
  constexpr size_t SZ_UBF   = (size_t)ROWS*DMODEL*2;
  constexpr size_t OFF_WIN  = OFF_UBF + SZ_UBF;
  constexpr size_t SZ_WIN   = (size_t)ZPAD*DMODEL*2;
  constexpr size_t OFF_WOUT = OFF_WIN + SZ_WIN;
  constexpr size_t SZ_WOUT  = (size_t)DMODEL*EDIM*2;
  constexpr size_t OFF_X    = OFF_WOUT + SZ_WOUT;   // xraw (ROWS fp32)
  constexpr size_t SZ_X     = (size_t)ROWS*EDIM*2;
  constexpr size_t OFF_G    = OFF_X + SZ_X;
  constexpr size_t OFF_ZS   = OFF_G + SZ_X;
  constexpr size_t SZ_ZS    = (size_t)ROWS*384*4;
  constexpr size_t OFF_BN   = OFF_ZS + SZ_ZS;
  constexpr size_t SZ_BN    = (size_t)ROWS*128*4;
  constexpr size_t OFF_CN   = OFF_BN + SZ_BN;
  constexpr size_t OFF_DTTH = OFF_CN + SZ_BN;
  constexpr size_t SZ_DTTH  = (size_t)ROWS*64*4;
  constexpr size_t OFF_DT   = OFF_DTTH + SZ_DTTH;
  constexpr size_t OFF_AL   = OFF_DT  + (size_t)ROWS*4;
  constexpr size_t OFF_LAM  = OFF_AL  + (size_t)ROWS*4;
  constexpr size_t OFF_XB   = OFF_LAM + (size_t)ROWS*4;
  constexpr size_t OFF_OUTS = OFF_XB  + (size_t)ROWS*4;
  constexpr size_t OFF_YLOC = OFF_OUTS + (size_t)ROWS*4;
  constexpr size_t OFF_PFIX = OFF_YLOC + (size_t)ROWS*4;
  constexpr size_t OFF_SFIN = OFF_PFIX + (size_t)ROWS*4;
  constexpr size_t SZ_SFIN  = (size_t)B_SZ*SCHUNK*128*4;
  constexpr size_t OFF_DCH  = OFF_SFIN + SZ_SFIN;
  constexpr size_t OFF_SIN  = OFF_DCH + (size_t)B_SZ*SCHUNK*4;
  constexpr size_t OFF_CSUM = OFF_SIN + SZ_SFIN;

  float*  Asum   = (float*) (ws + OFF_ASUM);
  bf16_t* ubf    = (bf16_t*)(ws + OFF_UBF);
  bf16_t* winbf  = (bf16_t*)(ws + OFF_WIN);
  bf16_t* woutbf = (bf16_t*)(ws + OFF_WOUT);
  float*  xraw   = (float*) (ws + OFF_X);
  bf16_t* gbuf   = (bf16_t*)(ws + OFF_G);
  float*  zsb    = (float*) (ws + OFF_ZS);
  float*  Bn     = (float*) (ws + OFF_BN);
  float*  Cn     = (float*) (ws + OFF_CN);
  float*  dtth   = (float*) (ws + OFF_DTTH);
  float*  dts    = (float*) (ws + OFF_DT);
  float*  alphas = (float*) (ws + OFF_AL);
  float*  lams   = (float*) (ws + OFF_LAM);
  float*  xbar   = (float*) (ws + OFF_XB);
  float*  outsv  = (float*) (ws + OFF_OUTS);
  float*  ylocal = (float*) (ws + OFF_YLOC);
  float*  Pfix   = (float*) (ws + OFF_PFIX);
  float*  Sfin   = (float*) (ws + OFF_SFIN);
  float*  Dch    = (float*) (ws + OFF_DCH);
  float*  Sin    = (float*) (ws + OFF_SIN);
  float*  csum   = (float*) (ws + OFF_CSUM);

  {
    size_t total = (size_t)ROWS*DMODEL + (size_t)ZPAD*DMODEL + (size_t)DMODEL*EDIM;
    int blocks = (int)((total + 255)/256);
    prep_kernel<<<blocks, 256, 0, stream>>>(u, W_in, Wout, ubf, winbf, woutbf, Asum, xraw);
  }
  // GEMM1: M=8192 (BM=128, 64 tiles), N=4608 (18 tiles) -> 1152 blocks
  gemmDP_kernel<128, DMODEL, ZPAD/256, 0><<<(ZPAD/256)*(ROWS/128), 512, 0, stream>>>(
      ubf, winbf, xraw, gbuf, zsb, nullptr, nullptr);
  fuse_kernel<<<ROWS, 128, 0, stream>>>(xraw, zsb, wnB, wnC, Bb, Cb, dtb, Alog,
                                        Bn, Cn, dtth, dts, alphas, lams, xbar, Asum);
  rope_sum_kernel<<<B_SZ*RCH, 64, 0, stream>>>(dtth, csum);
  rope_prefix_kernel<<<B_SZ, 64, 0, stream>>>(csum);
  rope_apply_kernel<<<B_SZ*RCH, 64, 0, stream>>>(dtth, csum, Bn, Cn);
  scan_local_kernel<<<B_SZ*SCHUNK, 64, 0, stream>>>(dts, alphas, lams, xbar, Asum,
                                                    Bn, Cn, ylocal, Pfix, Sfin, Dch);
  scan_carry_kernel<<<B_SZ, 128, 0, stream>>>(Sfin, Dch, Sin);
  scan_fix_kernel<<<ROWS/4, 256, 0, stream>>>(Cn, Sin, ylocal, Pfix, outsv);
  // GEMM2: M=8192 (64 tiles), N=1024 (4 tiles) -> 256 blocks = 1/CU
  gemmDP_kernel<128, EDIM, DMODEL/256, 1><<<(DMODEL/256)*(ROWS/128), 512, 0, stream>>>(
      gbuf, woutbf, nullptr, nullptr, nullptr, outsv, out);
}

// Round 5
// 332.796 us; speedup vs baseline: 5.4421x; 1.0158x over previous
//
#include <hip/hip_runtime.h>
#include <cstdint>
#include <cstddef>

typedef __bf16 bf16_t;
typedef bf16_t bf16x8 __attribute__((ext_vector_type(8)));
typedef float f32x4 __attribute__((ext_vector_type(4)));

#define B_SZ    4
#define LSEQ    2048
#define DMODEL  1024
#define EDIM    2048
#define ZDIM    4419
#define ZPAD    4608            /* padded to 18 x 256 tiles */
#define ROWS    (B_SZ*LSEQ)     /* 8192 */
#define EPSV    1e-5f

/* padded leading dims (break power-of-2 L2-set/channel aliasing) */
#define LDU     1088            /* ubf, winbf rows of K=1024 */
#define LDG     2112            /* gbuf, woutbf rows of K=2048 */

#define SCHUNK  128             /* scan chunks per batch */
#define SCLEN   (LSEQ/SCHUNK)   /* 16 */
#define RCH     128             /* rope chunks per batch */
#define RCLEN   (LSEQ/RCH)      /* 16 */

// ---------------- helpers ----------------
__device__ __forceinline__ float softplus_f(float x){
  return fmaxf(x, 0.f) + log1pf(expf(-fabsf(x)));
}
__device__ __forceinline__ float sigmoid_f(float x){ return 1.f/(1.f+expf(-x)); }
__device__ __forceinline__ float silu_f(float x){ return x/(1.f+expf(-x)); }

__device__ __forceinline__ void gload_lds16(const void* g, void* l){
  __builtin_amdgcn_global_load_lds(
      (const __attribute__((address_space(1))) void*)g,
      (__attribute__((address_space(3))) void*)l, 16, 0, 0);
}

__device__ __forceinline__ float blockReduce128(float v, float* red, int t){
  red[t] = v; __syncthreads();
  #pragma unroll
  for (int off = 64; off > 0; off >>= 1){
    if (t < off) red[t] += red[t+off];
    __syncthreads();
  }
  float r = red[0];
  __syncthreads();
  return r;
}

// ---------------- kernel 0: casts + zero accumulators (padded strides) -----
__global__ __launch_bounds__(256) void prep_kernel(
    const float* __restrict__ u, const float* __restrict__ win, const float* __restrict__ wout,
    bf16_t* __restrict__ ubf, bf16_t* __restrict__ winbf, bf16_t* __restrict__ woutbf,
    float* __restrict__ Asum, float* __restrict__ xraw)
{
  size_t i = (size_t)blockIdx.x*256 + threadIdx.x;
  if (i == 0) Asum[0] = 0.f;
  if (i < ROWS) xraw[i] = 0.f;
  const size_t NU = (size_t)ROWS*DMODEL;
  const size_t NW = (size_t)ZPAD*DMODEL;
  const size_t NO = (size_t)DMODEL*EDIM;
  if (i < NU){
    size_t row = i >> 10, col = i & 1023;
    ubf[row*LDU + col] = (bf16_t)u[i];
    return;
  }
  i -= NU;
  if (i < NW){
    size_t row = i >> 10, col = i & 1023;
    winbf[row*LDU + col] = (row < (size_t)ZDIM) ? (bf16_t)win[i] : (bf16_t)0.f;
    return;
  }
  i -= NW;
  if (i < NO){
    size_t row = i >> 11, col = i & 2047;
    woutbf[row*LDG + col] = (bf16_t)wout[i];
  }
}

// ---------------- phase-split deep-pipelined GEMM (T1+T2+T3/T4+T5) ---------
// C = A[M][lda] @ W[N][ldw]^T (bf16, row-major, K = NT*64).
// BM=128, BN=256, BK=64, 512 thr = 8 waves (2M x 4N), per-wave 64x64 output.
// 3 LDS buffers (144 KB), depth-2 prefetch. Per K-tile: 2 phases
// {8 x ds_read || stage-half || barrier || lgkmcnt(0) || setprio+16 MFMA || barrier},
// vmcnt counted 8/6/0 (never 0 in steady state). T2 chunk-XOR swizzle both
// sides; bijective XCD swizzle.
// MODE 0 (GEMM1): x-region -> silu row-sum atomics into xraw;
//                 gate-region -> silu -> o_g (stride LDG); z-region -> o_z fp32.
// MODE 1 (GEMM2): out = acc * scale[row] -> o_f fp32 (stride DMODEL).
template<int BM, int NT, int NXT, int MODE>
__global__ __launch_bounds__(512, 2) void gemmP_kernel(
    const bf16_t* __restrict__ A, const int lda,
    const bf16_t* __restrict__ W, const int ldw,
    float* __restrict__ xraw, bf16_t* __restrict__ o_g, float* __restrict__ o_z,
    const float* __restrict__ scale, float* __restrict__ o_f)
{
  constexpr int BN = 256;
  constexpr int MR = BM/32;             // 4
  constexpr int BUFE = (BM+BN)*64;
  __shared__ __align__(16) bf16_t lds[BUFE*3];

  const int tid = threadIdx.x;
  const int wid = tid>>6, lane = tid&63;
  const int wr = wid>>2, wc = wid&3;
  const int lr = lane&15;

  const int nwg = NXT*(ROWS/BM);
  const int id = blockIdx.x;
  const int rid = (id & 7)*(nwg>>3) + (id>>3);   // bijective: nwg % 8 == 0
  const int bx = rid % NXT, by = rid / NXT;
  const int m0 = by*BM, n0 = bx*BN;

  f32x4 acc[MR][4] = {};

  auto stageA = [&](int buf, int t){              // 2 loads/thread
    bf16_t* lA = lds + buf*BUFE;
    const int k0 = t*64;
    #pragma unroll
    for (int q = 0; q < BM/64; ++q){
      int cidx = q*512 + tid;
      int row = cidx>>3, sc = (cidx&7) ^ (row&7);
      gload_lds16(A + (size_t)(m0+row)*lda + k0 + sc*8,
                  lA + (size_t)(q*512 + wid*64)*8);
    }
  };
  auto stageB = [&](int buf, int t){              // 4 loads/thread
    bf16_t* lB = lds + buf*BUFE + BM*64;
    const int k0 = t*64;
    #pragma unroll
    for (int q = 0; q < 4; ++q){
      int cidx = q*512 + tid;
      int row = cidx>>3, sc = (cidx&7) ^ (row&7);
      gload_lds16(W + (size_t)(n0+row)*ldw + k0 + sc*8,
                  lB + (size_t)(q*512 + wid*64)*8);
    }
  };
  auto dsread = [&](int buf, int kk, bf16x8* af, bf16x8* bfr){
    const bf16_t* lA = lds + buf*BUFE;
    const bf16_t* lB = lA + BM*64;
    const int g = kk*4 + (lane>>4);
    #pragma unroll
    for (int n = 0; n < 4; ++n){
      int rr = wc*64 + n*16 + lr;
      bfr[n] = *(const bf16x8*)&lB[rr*64 + ((g^(rr&7))<<3)];
    }
    #pragma unroll
    for (int m = 0; m < MR; ++m){
      int rr = wr*(BM/2) + m*16 + lr;
      af[m] = *(const bf16x8*)&lA[rr*64 + ((g^(rr&7))<<3)];
    }
  };
  auto domfma = [&](bf16x8* af, bf16x8* bfr){
    asm volatile("s_waitcnt lgkmcnt(0)" ::: "memory");
    __builtin_amdgcn_sched_barrier(0);
    __builtin_amdgcn_s_setprio(1);
    #pragma unroll
    for (int m = 0; m < MR; ++m)
      #pragma unroll
      for (int n = 0; n < 4; ++n)
        acc[m][n] = __builtin_amdgcn_mfma_f32_16x16x32_bf16(af[m], bfr[n], acc[m][n], 0,0,0);
    __builtin_amdgcn_s_setprio(0);
  };

  stageA(0,0); stageB(0,0);
  stageA(1,1); stageB(1,1);
  int cur = 0;
  for (int t = 0; t < NT; ++t){
    int nb = cur+2; if (nb >= 3) nb -= 3;
    const bool st = (t+2 < NT);
    if (st){
      stageA(nb, t+2);
      asm volatile("s_waitcnt vmcnt(8)" ::: "memory");   // 6 (tile t+1) + 2 just issued
    } else if (t+1 < NT){
      asm volatile("s_waitcnt vmcnt(6)" ::: "memory");
    } else {
      asm volatile("s_waitcnt vmcnt(0)" ::: "memory");
    }
    asm volatile("s_barrier" ::: "memory");
    {
      bf16x8 af[MR], bfr[4];
      dsread(cur, 0, af, bfr);
      domfma(af, bfr);
    }
    asm volatile("s_barrier" ::: "memory");
    {
      bf16x8 af[MR], bfr[4];
      dsread(cur, 1, af, bfr);
      if (st) stageB(nb, t+2);
      domfma(af, bfr);
    }
    asm volatile("s_barrier" ::: "memory");
    if (++cur == 3) cur = 0;
  }

  // ---- epilogue (branch uniform per block: region boundaries 256-aligned)
  if (MODE == 0 && n0 < 2048){
    // x region: only the per-row silu mean is needed downstream
    #pragma unroll
    for (int m = 0; m < MR; ++m){
      #pragma unroll
      for (int i = 0; i < 4; ++i){
        float p = 0.f;
        #pragma unroll
        for (int n = 0; n < 4; ++n) p += silu_f(acc[m][n][i]);
        #pragma unroll
        for (int off = 8; off > 0; off >>= 1) p += __shfl_xor(p, off);
        if (lr == 0){
          int r = m0 + wr*(BM/2) + m*16 + ((lane>>4)<<2) + i;
          atomicAdd(xraw + r, p);
        }
      }
    }
  } else {
    #pragma unroll
    for (int m = 0; m < MR; ++m){
      int rowb = m0 + wr*(BM/2) + m*16 + ((lane>>4)<<2);
      #pragma unroll
      for (int n = 0; n < 4; ++n){
        int col = n0 + wc*64 + n*16 + lr;
        #pragma unroll
        for (int i = 0; i < 4; ++i){
          int r = rowb + i;
          float v = acc[m][n][i];
          if (MODE == 0){
            if (col < 4096)      o_g[(size_t)r*LDG + (col-2048)] = (bf16_t)silu_f(v);
            else if (col < 4480) o_z[(size_t)r*384 + (col-4096)] = v;
          } else {
            o_f[(size_t)r*DMODEL + col] = v * scale[r];
          }
        }
      }
    }
  }
}

// ---------------- kernel 2: per-token fuse (RMS + scalars) ----------------
__global__ __launch_bounds__(128) void fuse_kernel(
    const float* __restrict__ xraw, const float* __restrict__ zs,
    const float* __restrict__ wnB, const float* __restrict__ wnC,
    const float* __restrict__ Bb, const float* __restrict__ Cb,
    const float* __restrict__ dtb, const float* __restrict__ Alog,
    float* __restrict__ Bn, float* __restrict__ Cn, float* __restrict__ dtth,
    float* __restrict__ dts, float* __restrict__ alphas, float* __restrict__ lams,
    float* __restrict__ xbar, float* Asum)
{
  __shared__ float red[128];
  int r = blockIdx.x, t = threadIdx.x;
  const float* zr = zs + (size_t)r*384;
  float bv = zr[t], cv = zr[128+t];
  float b2 = blockReduce128(bv*bv, red, t);
  float c2 = blockReduce128(cv*cv, red, t);
  float rb = rsqrtf(b2*(1.f/128.f) + EPSV);
  float rc = rsqrtf(c2*(1.f/128.f) + EPSV);
  Bn[(size_t)r*128 + t] = bv*rb*wnB[t] + Bb[t];
  Cn[(size_t)r*128 + t] = cv*rc*wnC[t] + Cb[t];

  float dt = softplus_f(zr[256] + dtb[0]);
  if (t < 64) dtth[(size_t)r*64 + t] = dt * zr[258+t];
  if (t == 0){
    float Av  = -softplus_f(zr[257] + Alog[0]);
    float lam = sigmoid_f(zr[322]);
    dts[r]    = dt;
    alphas[r] = expf(dt*Av);
    lams[r]   = lam;
    xbar[r]   = xraw[r] * (1.f/2048.f);
    atomicAdd(Asum, Av);
  }
}

// ---------------- kernel 3a: per-chunk angle sums ----------------
__global__ __launch_bounds__(64) void rope_sum_kernel(
    const float* __restrict__ dtth, float* __restrict__ csum)
{
  int b  = blockIdx.x >> 7;
  int ch = blockIdx.x & 127;
  int d  = threadIdx.x;
  const float* base = dtth + ((size_t)b*LSEQ + (size_t)ch*RCLEN)*64 + d;
  float s = 0.f;
  #pragma unroll
  for (int i = 0; i < RCLEN; ++i) s += base[(size_t)i*64];
  csum[((size_t)b*RCH + ch)*64 + d] = s;
}

// ---------------- kernel 3b: exclusive prefix over chunks (in place) -------
__global__ __launch_bounds__(64) void rope_prefix_kernel(float* __restrict__ csum)
{
  int b = blockIdx.x, d = threadIdx.x;
  float s = 0.f;
  for (int c = 0; c < RCH; ++c){
    size_t idx = ((size_t)b*RCH + c)*64 + d;
    float v = csum[idx]; csum[idx] = s; s += v;
  }
}

// ---------------- kernel 3c: rope apply with chunk offsets ----------------
__global__ __launch_bounds__(64) void rope_apply_kernel(
    const float* __restrict__ dtth, const float* __restrict__ csum,
    float* __restrict__ Bn, float* __restrict__ Cn)
{
  int b  = blockIdx.x >> 7;
  int ch = blockIdx.x & 127;
  int d  = threadIdx.x;
  float ca = csum[((size_t)b*RCH + ch)*64 + d];
  int l0 = ch*RCLEN;
  const float* base = dtth + ((size_t)b*LSEQ)*64 + d;
  for (int l = l0; l < l0 + RCLEN; ++l){
    ca += base[(size_t)l*64];
    float sn, cs;
    sincosf(ca, &sn, &cs);
    size_t ro = ((size_t)b*LSEQ + l)*128;
    float b1 = Bn[ro+d], b2v = Bn[ro+64+d];
    Bn[ro+d]    = b1*cs - b2v*sn;
    Bn[ro+64+d] = b1*sn + b2v*cs;
    float c1 = Cn[ro+d], c2v = Cn[ro+64+d];
    Cn[ro+d]    = c1*cs - c2v*sn;
    Cn[ro+64+d] = c1*sn + c2v*cs;
  }
}

// ---------------- kernel 4a: chunk-local scan ----------------
__global__ __launch_bounds__(64) void scan_local_kernel(
    const float* __restrict__ dts, const float* __restrict__ alphas,
    const float* __restrict__ lams, const float* __restrict__ xbar,
    const float* __restrict__ Asum,
    const float* __restrict__ Bn, const float* __restrict__ Cn,
    float* __restrict__ ylocal, float* __restrict__ Pfix,
    float* __restrict__ Sfin, float* __restrict__ Dch)
{
  int b  = blockIdx.x / SCHUNK;
  int ch = blockIdx.x % SCHUNK;
  int n  = threadIdx.x;
  float Abar = Asum[0] * (1.f/(float)ROWS);
  float s1 = 0.f, s2 = 0.f, P = 1.f;
  int l0 = ch*SCLEN;
  #pragma unroll
  for (int i = 0; i < SCLEN; ++i){
    int l = l0 + i;
    size_t r = (size_t)b*LSEQ + l;
    float dt = dts[r], lam = lams[r], al = alphas[r], xb = xbar[r];
    float xp = (l > 0) ? xbar[r-1] : 0.f;
    float um = lam*xb + (1.f-lam)*al*xp;
    float dA = expf(dt*Abar);
    float coef = dt*um;
    size_t ro = r*128;
    s1 = dA*s1 + coef*Bn[ro+n];
    s2 = dA*s2 + coef*Bn[ro+64+n];
    P *= dA;
    float p = s1*Cn[ro+n] + s2*Cn[ro+64+n];
    #pragma unroll
    for (int off = 32; off > 0; off >>= 1) p += __shfl_down(p, off);
    if (n == 0){ ylocal[r] = p; Pfix[r] = P; }
  }
  size_t so = ((size_t)b*SCHUNK + ch)*128;
  Sfin[so + n]      = s1;
  Sfin[so + 64 + n] = s2;
  if (n == 0) Dch[b*SCHUNK + ch] = P;
}

// ---------------- kernel 4b: inter-chunk carry ----------------
__global__ __launch_bounds__(128) void scan_carry_kernel(
    const float* __restrict__ Sfin, const float* __restrict__ Dch,
    float* __restrict__ Sin)
{
  int b = blockIdx.x;
  int n = threadIdx.x;   // 0..127
  float s = 0.f;
  for (int c = 0; c < SCHUNK; ++c){
    size_t so = ((size_t)b*SCHUNK + c)*128;
    Sin[so + n] = s;
    s = Dch[b*SCHUNK + c]*s + Sfin[so + n];
  }
}

// ---------------- kernel 4c: fixup  y = y_local + P_l * (C_l . Sin) --------
__global__ __launch_bounds__(256) void scan_fix_kernel(
    const float* __restrict__ Cn, const float* __restrict__ Sin,
    const float* __restrict__ ylocal, const float* __restrict__ Pfix,
    float* __restrict__ outsv)
{
  int r = blockIdx.x*4 + (threadIdx.x>>6);
  int n = threadIdx.x & 63;
  int b  = r / LSEQ;
  int ch = (r % LSEQ) / SCLEN;
  const float* si = Sin + ((size_t)b*SCHUNK + ch)*128;
  size_t ro = (size_t)r*128;
  float p = Cn[ro+n]*si[n] + Cn[ro+64+n]*si[64+n];
  #pragma unroll
  for (int off = 32; off > 0; off >>= 1) p += __shfl_down(p, off);
  if (n == 0) outsv[r] = ylocal[r] + Pfix[r]*p;
}

// ---------------- launch ----------------
extern "C" void kernel_launch(void* const* d_in, const int* in_sizes, int n_in,
                              void* d_out, int out_size, void* d_ws, size_t ws_size,
                              hipStream_t stream)
{
  const float* u    = (const float*)d_in[0];
  const float* W_in = (const float*)d_in[1];
  const float* wnB  = (const float*)d_in[2];
  const float* wnC  = (const float*)d_in[3];
  const float* Bb   = (const float*)d_in[4];
  const float* Cb   = (const float*)d_in[5];
  const float* dtb  = (const float*)d_in[6];
  const float* Alog = (const float*)d_in[7];
  const float* Wout = (const float*)d_in[8];
  float* out = (float*)d_out;
  char* ws = (char*)d_ws;

  constexpr size_t OFF_ASUM = 0;
  constexpr size_t OFF_UBF  = 256;
  constexpr size_t SZ_UBF   = (size_t)ROWS*LDU*2;       // 17,825,792
  constexpr size_t OFF_WIN  = OFF_UBF + SZ_UBF;
  constexpr size_t SZ_WIN   = (size_t)ZPAD*LDU*2;       // 10,027,008
  constexpr size_t OFF_WOUT = OFF_WIN + SZ_WIN;
  constexpr size_t SZ_WOUT  = (size_t)DMODEL*LDG*2;     // 4,325,376
  constexpr size_t OFF_G    = OFF_WOUT + SZ_WOUT;
  constexpr size_t SZ_G     = (size_t)ROWS*LDG*2;       // 34,603,008
  constexpr size_t OFF_ZS   = OFF_G + SZ_G;
  constexpr size_t SZ_ZS    = (size_t)ROWS*384*4;
  constexpr size_t OFF_BN   = OFF_ZS + SZ_ZS;
  constexpr size_t SZ_BN    = (size_t)ROWS*128*4;
  constexpr size_t OFF_CN   = OFF_BN + SZ_BN;
  constexpr size_t OFF_DTTH = OFF_CN + SZ_BN;
  constexpr size_t SZ_DTTH  = (size_t)ROWS*64*4;
  constexpr size_t OFF_XRAW = OFF_DTTH + SZ_DTTH;
  constexpr size_t OFF_DT   = OFF_XRAW + (size_t)ROWS*4;
  constexpr size_t OFF_AL   = OFF_DT  + (size_t)ROWS*4;
  constexpr size_t OFF_LAM  = OFF_AL  + (size_t)ROWS*4;
  constexpr size_t OFF_XB   = OFF_LAM + (size_t)ROWS*4;
  constexpr size_t OFF_OUTS = OFF_XB  + (size_t)ROWS*4;
  constexpr size_t OFF_YLOC = OFF_OUTS + (size_t)ROWS*4;
  constexpr size_t OFF_PFIX = OFF_YLOC + (size_t)ROWS*4;
  constexpr size_t OFF_SFIN = OFF_PFIX + (size_t)ROWS*4;
  constexpr size_t SZ_SFIN  = (size_t)B_SZ*SCHUNK*128*4;
  constexpr size_t OFF_DCH  = OFF_SFIN + SZ_SFIN;
  constexpr size_t OFF_SIN  = OFF_DCH + (size_t)B_SZ*SCHUNK*4;
  constexpr size_t OFF_CSUM = OFF_SIN + SZ_SFIN;

  float*  Asum   = (float*) (ws + OFF_ASUM);
  bf16_t* ubf    = (bf16_t*)(ws + OFF_UBF);
  bf16_t* winbf  = (bf16_t*)(ws + OFF_WIN);
  bf16_t* woutbf = (bf16_t*)(ws + OFF_WOUT);
  bf16_t* gbuf   = (bf16_t*)(ws + OFF_G);
  float*  zsb    = (float*) (ws + OFF_ZS);
  float*  Bn     = (float*) (ws + OFF_BN);
  float*  Cn     = (float*) (ws + OFF_CN);
  float*  dtth   = (float*) (ws + OFF_DTTH);
  float*  xraw   = (float*) (ws + OFF_XRAW);
  float*  dts    = (float*) (ws + OFF_DT);
  float*  alphas = (float*) (ws + OFF_AL);
  float*  lams   = (float*) (ws + OFF_LAM);
  float*  xbar   = (float*) (ws + OFF_XB);
  float*  outsv  = (float*) (ws + OFF_OUTS);
  float*  ylocal = (float*) (ws + OFF_YLOC);
  float*  Pfix   = (float*) (ws + OFF_PFIX);
  float*  Sfin   = (float*) (ws + OFF_SFIN);
  float*  Dch    = (float*) (ws + OFF_DCH);
  float*  Sin    = (float*) (ws + OFF_SIN);
  float*  csum   = (float*) (ws + OFF_CSUM);

  {
    size_t total = (size_t)ROWS*DMODEL + (size_t)ZPAD*DMODEL + (size_t)DMODEL*EDIM;
    int blocks = (int)((total + 255)/256);
    prep_kernel<<<blocks, 256, 0, stream>>>(u, W_in, Wout, ubf, winbf, woutbf, Asum, xraw);
  }
  // GEMM1: M=8192 (64 BM-tiles), N=4608 (18 BN-tiles) -> 1152 blocks
  gemmP_kernel<128, DMODEL/64, ZPAD/256, 0><<<(ZPAD/256)*(ROWS/128), 512, 0, stream>>>(
      ubf, LDU, winbf, LDU, xraw, gbuf, zsb, nullptr, nullptr);
  fuse_kernel<<<ROWS, 128, 0, stream>>>(xraw, zsb, wnB, wnC, Bb, Cb, dtb, Alog,
                                        Bn, Cn, dtth, dts, alphas, lams, xbar, Asum);
  rope_sum_kernel<<<B_SZ*RCH, 64, 0, stream>>>(dtth, csum);
  rope_prefix_kernel<<<B_SZ, 64, 0, stream>>>(csum);
  rope_apply_kernel<<<B_SZ*RCH, 64, 0, stream>>>(dtth, csum, Bn, Cn);
  scan_local_kernel<<<B_SZ*SCHUNK, 64, 0, stream>>>(dts, alphas, lams, xbar, Asum,
                                                    Bn, Cn, ylocal, Pfix, Sfin, Dch);
  scan_carry_kernel<<<B_SZ, 128, 0, stream>>>(Sfin, Dch, Sin);
  scan_fix_kernel<<<ROWS/4, 256, 0, stream>>>(Cn, Sin, ylocal, Pfix, outsv);
  // GEMM2: M=8192 (64 tiles), N=1024 (4 tiles) -> 256 blocks = 1/CU
  gemmP_kernel<128, EDIM/64, DMODEL/256, 1><<<(DMODEL/256)*(ROWS/128), 512, 0, stream>>>(
      gbuf, LDG, woutbf, LDG, nullptr, nullptr, nullptr, outsv, out);
}

// Round 6
// 323.034 us; speedup vs baseline: 5.6065x; 1.0302x over previous
//
#include <hip/hip_runtime.h>
#include <cstdint>
#include <cstddef>

typedef __bf16 bf16_t;
typedef bf16_t bf16x8 __attribute__((ext_vector_type(8)));
typedef bf16_t bf16x4 __attribute__((ext_vector_type(4)));
typedef float f32x4 __attribute__((ext_vector_type(4)));

#define B_SZ    4
#define LSEQ    2048
#define DMODEL  1024
#define EDIM    2048
#define ZDIM    4419
#define ZPAD    4608            /* padded to 18 x 256 tiles */
#define ROWS    (B_SZ*LSEQ)     /* 8192 */
#define EPSV    1e-5f

/* padded leading dims (break power-of-2 L2-set/channel aliasing) */
#define LDU     1088            /* ubf, winbf rows of K=1024 */
#define LDG     2112            /* gbuf, woutbf rows of K=2048 */

#define SCHUNK  128             /* scan chunks per batch */
#define SCLEN   (LSEQ/SCHUNK)   /* 16 */
#define RCH     128             /* rope chunks per batch */
#define RCLEN   (LSEQ/RCH)      /* 16 */

// ---------------- helpers ----------------
__device__ __forceinline__ float softplus_f(float x){
  return fmaxf(x, 0.f) + log1pf(expf(-fabsf(x)));
}
__device__ __forceinline__ float sigmoid_f(float x){ return 1.f/(1.f+expf(-x)); }
__device__ __forceinline__ float silu_f(float x){ return x/(1.f+expf(-x)); }

__device__ __forceinline__ void gload_lds16(const void* g, void* l){
  __builtin_amdgcn_global_load_lds(
      (const __attribute__((address_space(1))) void*)g,
      (__attribute__((address_space(3))) void*)l, 16, 0, 0);
}

__device__ __forceinline__ float blockReduce128(float v, float* red, int t){
  red[t] = v; __syncthreads();
  #pragma unroll
  for (int off = 64; off > 0; off >>= 1){
    if (t < off) red[t] += red[t+off];
    __syncthreads();
  }
  float r = red[0];
  __syncthreads();
  return r;
}

// ---------------- kernel 0: vectorized casts + zero accumulators -----------
__global__ __launch_bounds__(256) void prep_kernel(
    const float4* __restrict__ u4, const float4* __restrict__ win4,
    const float4* __restrict__ wout4,
    bf16_t* __restrict__ ubf, bf16_t* __restrict__ winbf, bf16_t* __restrict__ woutbf,
    float* __restrict__ Asum, float* __restrict__ xraw)
{
  size_t i = (size_t)blockIdx.x*256 + threadIdx.x;   // float4 index
  if (i == 0) Asum[0] = 0.f;
  if (i < ROWS) xraw[i] = 0.f;
  const size_t NU4 = (size_t)ROWS*DMODEL/4;
  const size_t NW4 = (size_t)ZPAD*DMODEL/4;
  const size_t NO4 = (size_t)DMODEL*EDIM/4;
  if (i < NU4){
    float4 v = u4[i];
    size_t e = i*4, row = e>>10, col = e&1023;
    bf16x4 o = { (bf16_t)v.x, (bf16_t)v.y, (bf16_t)v.z, (bf16_t)v.w };
    *(bf16x4*)&ubf[row*LDU + col] = o;
    return;
  }
  i -= NU4;
  if (i < NW4){
    size_t e = i*4, row = e>>10, col = e&1023;
    bf16x4 o;
    if (row < (size_t)ZDIM){
      float4 v = win4[i];
      o = bf16x4{ (bf16_t)v.x, (bf16_t)v.y, (bf16_t)v.z, (bf16_t)v.w };
    } else {
      o = bf16x4{ (bf16_t)0.f, (bf16_t)0.f, (bf16_t)0.f, (bf16_t)0.f };
    }
    *(bf16x4*)&winbf[row*LDU + col] = o;
    return;
  }
  i -= NW4;
  if (i < NO4){
    float4 v = wout4[i];
    size_t e = i*4, row = e>>11, col = e&2047;
    bf16x4 o = { (bf16_t)v.x, (bf16_t)v.y, (bf16_t)v.z, (bf16_t)v.w };
    *(bf16x4*)&woutbf[row*LDG + col] = o;
  }
}

// ---------------- high-intensity 2-buffer GEMM (T1+T2+T4+T5) ----------------
// C = A[M][lda] @ W[N][ldw]^T (bf16 row-major, K = NT*64).
// BM x BN tile, BK=64, 512 thr = 8 waves (WM x WN wave grid).
// 2 LDS buffers; per K-tile: stageA(t+1) -> vmcnt(4) -> barrier ->
// {ds_read kk0 + MFMA} -> stageB(t+1) -> {ds_read kk1 + MFMA} -> barrier.
// Counted vmcnt: B loads get ~1 tile, A loads ~1.5 tiles to land.
// T2 chunk-XOR swizzle both sides; bijective XCD swizzle.
// MODE 0 (GEMM1, BM=256 BN=256): x-region -> silu row-sum atomics into xraw;
//   gate -> silu -> o_g (stride LDG); z -> o_z fp32.
// MODE 1 (GEMM2, BM=256 BN=128): out = acc * scale[row] -> o_f fp32.
template<int BM, int BN, int WM, int WN, int NT, int NXT, int MODE>
__global__ __launch_bounds__(512, 2) void gemmQ_kernel(
    const bf16_t* __restrict__ A, const int lda,
    const bf16_t* __restrict__ W, const int ldw,
    float* __restrict__ xraw, bf16_t* __restrict__ o_g, float* __restrict__ o_z,
    const float* __restrict__ scale, float* __restrict__ o_f)
{
  constexpr int MR = BM/WM/16;
  constexpr int NR = BN/WN/16;
  constexpr int LA = BM/64;            // A loads/thread/tile
  constexpr int LB = BN/64;            // B loads/thread/tile
  constexpr int BUFE = (BM+BN)*64;
  __shared__ __align__(16) bf16_t lds[BUFE*2];

  const int tid = threadIdx.x;
  const int wid = tid>>6, lane = tid&63;
  const int wr = wid / WN, wc = wid % WN;
  const int lr = lane&15;

  const int nwg = NXT*(ROWS/BM);
  const int id = blockIdx.x;
  const int rid = (id & 7)*(nwg>>3) + (id>>3);   // bijective: nwg % 8 == 0
  const int bx = rid % NXT, by = rid / NXT;
  const int m0 = by*BM, n0 = bx*BN;

  f32x4 acc[MR][NR] = {};

  auto stageA = [&](int buf, int t){
    bf16_t* lA = lds + buf*BUFE;
    const int k0 = t*64;
    #pragma unroll
    for (int q = 0; q < LA; ++q){
      int cidx = q*512 + tid;
      int row = cidx>>3, sc = (cidx&7) ^ (row&7);
      gload_lds16(A + (size_t)(m0+row)*lda + k0 + sc*8,
                  lA + (size_t)(q*512 + wid*64)*8);
    }
  };
  auto stageB = [&](int buf, int t){
    bf16_t* lB = lds + buf*BUFE + BM*64;
    const int k0 = t*64;
    #pragma unroll
    for (int q = 0; q < LB; ++q){
      int cidx = q*512 + tid;
      int row = cidx>>3, sc = (cidx&7) ^ (row&7);
      gload_lds16(W + (size_t)(n0+row)*ldw + k0 + sc*8,
                  lB + (size_t)(q*512 + wid*64)*8);
    }
  };
  auto phase = [&](int buf, int kk){
    const bf16_t* lA = lds + buf*BUFE;
    const bf16_t* lB = lA + BM*64;
    const int g = kk*4 + (lane>>4);
    bf16x8 af[MR], bfr[NR];
    #pragma unroll
    for (int n = 0; n < NR; ++n){
      int rr = wc*(BN/WN) + n*16 + lr;
      bfr[n] = *(const bf16x8*)&lB[rr*64 + ((g^(rr&7))<<3)];
    }
    #pragma unroll
    for (int m = 0; m < MR; ++m){
      int rr = wr*(BM/WM) + m*16 + lr;
      af[m] = *(const bf16x8*)&lA[rr*64 + ((g^(rr&7))<<3)];
    }
    asm volatile("s_waitcnt lgkmcnt(0)" ::: "memory");
    __builtin_amdgcn_sched_barrier(0);
    __builtin_amdgcn_s_setprio(1);
    #pragma unroll
    for (int m = 0; m < MR; ++m)
      #pragma unroll
      for (int n = 0; n < NR; ++n)
        acc[m][n] = __builtin_amdgcn_mfma_f32_16x16x32_bf16(af[m], bfr[n], acc[m][n], 0,0,0);
    __builtin_amdgcn_s_setprio(0);
  };

  stageA(0, 0); stageB(0, 0);
  int cur = 0;
  for (int t = 0; t < NT; ++t){
    const bool pf = (t+1 < NT);
    if (pf){
      stageA(cur^1, t+1);
      asm volatile("s_waitcnt vmcnt(4)" ::: "memory");  // drains tile t; A(t+1) stays in flight
    } else {
      asm volatile("s_waitcnt vmcnt(0)" ::: "memory");
    }
    asm volatile("s_barrier" ::: "memory");
    phase(cur, 0);
    if (pf) stageB(cur^1, t+1);
    phase(cur, 1);
    asm volatile("s_barrier" ::: "memory");
    cur ^= 1;
  }

  // ---- epilogue (branch uniform per block: region boundaries BN-aligned)
  if (MODE == 0 && n0 < 2048){
    // x region: only the per-row silu mean is needed downstream
    #pragma unroll
    for (int m = 0; m < MR; ++m){
      #pragma unroll
      for (int i = 0; i < 4; ++i){
        float p = 0.f;
        #pragma unroll
        for (int n = 0; n < NR; ++n) p += silu_f(acc[m][n][i]);
        #pragma unroll
        for (int off = 8; off > 0; off >>= 1) p += __shfl_xor(p, off);
        if (lr == 0){
          int r = m0 + wr*(BM/WM) + m*16 + ((lane>>4)<<2) + i;
          atomicAdd(xraw + r, p);
        }
      }
    }
  } else {
    #pragma unroll
    for (int m = 0; m < MR; ++m){
      int rowb = m0 + wr*(BM/WM) + m*16 + ((lane>>4)<<2);
      #pragma unroll
      for (int n = 0; n < NR; ++n){
        int col = n0 + wc*(BN/WN) + n*16 + lr;
        #pragma unroll
        for (int i = 0; i < 4; ++i){
          int r = rowb + i;
          float v = acc[m][n][i];
          if (MODE == 0){
            if (col < 4096)      o_g[(size_t)r*LDG + (col-2048)] = (bf16_t)silu_f(v);
            else if (col < 4480) o_z[(size_t)r*384 + (col-4096)] = v;
          } else {
            o_f[(size_t)r*DMODEL + col] = v * scale[r];
          }
        }
      }
    }
  }
}

// ---------------- kernel 2: per-token fuse (RMS + scalars) ----------------
__global__ __launch_bounds__(128) void fuse_kernel(
    const float* __restrict__ xraw, const float* __restrict__ zs,
    const float* __restrict__ wnB, const float* __restrict__ wnC,
    const float* __restrict__ Bb, const float* __restrict__ Cb,
    const float* __restrict__ dtb, const float* __restrict__ Alog,
    float* __restrict__ Bn, float* __restrict__ Cn, float* __restrict__ dtth,
    float* __restrict__ dts, float* __restrict__ alphas, float* __restrict__ lams,
    float* __restrict__ xbar, float* Asum)
{
  __shared__ float red[128];
  int r = blockIdx.x, t = threadIdx.x;
  const float* zr = zs + (size_t)r*384;
  float bv = zr[t], cv = zr[128+t];
  float b2 = blockReduce128(bv*bv, red, t);
  float c2 = blockReduce128(cv*cv, red, t);
  float rb = rsqrtf(b2*(1.f/128.f) + EPSV);
  float rc = rsqrtf(c2*(1.f/128.f) + EPSV);
  Bn[(size_t)r*128 + t] = bv*rb*wnB[t] + Bb[t];
  Cn[(size_t)r*128 + t] = cv*rc*wnC[t] + Cb[t];

  float dt = softplus_f(zr[256] + dtb[0]);
  if (t < 64) dtth[(size_t)r*64 + t] = dt * zr[258+t];
  if (t == 0){
    float Av  = -softplus_f(zr[257] + Alog[0]);
    float lam = sigmoid_f(zr[322]);
    dts[r]    = dt;
    alphas[r] = expf(dt*Av);
    lams[r]   = lam;
    xbar[r]   = xraw[r] * (1.f/2048.f);
    atomicAdd(Asum, Av);
  }
}

// ---------------- kernel 3a: per-chunk angle sums ----------------
__global__ __launch_bounds__(64) void rope_sum_kernel(
    const float* __restrict__ dtth, float* __restrict__ csum)
{
  int b  = blockIdx.x >> 7;
  int ch = blockIdx.x & 127;
  int d  = threadIdx.x;
  const float* base = dtth + ((size_t)b*LSEQ + (size_t)ch*RCLEN)*64 + d;
  float s = 0.f;
  #pragma unroll
  for (int i = 0; i < RCLEN; ++i) s += base[(size_t)i*64];
  csum[((size_t)b*RCH + ch)*64 + d] = s;
}

// ---------------- kernel 3b: exclusive prefix over chunks (in place) -------
__global__ __launch_bounds__(64) void rope_prefix_kernel(float* __restrict__ csum)
{
  int b = blockIdx.x, d = threadIdx.x;
  float s = 0.f;
  for (int c = 0; c < RCH; ++c){
    size_t idx = ((size_t)b*RCH + c)*64 + d;
    float v = csum[idx]; csum[idx] = s; s += v;
  }
}

// ---------------- kernel 3c: rope apply with chunk offsets ----------------
__global__ __launch_bounds__(64) void rope_apply_kernel(
    const float* __restrict__ dtth, const float* __restrict__ csum,
    float* __restrict__ Bn, float* __restrict__ Cn)
{
  int b  = blockIdx.x >> 7;
  int ch = blockIdx.x & 127;
  int d  = threadIdx.x;
  float ca = csum[((size_t)b*RCH + ch)*64 + d];
  int l0 = ch*RCLEN;
  const float* base = dtth + ((size_t)b*LSEQ)*64 + d;
  for (int l = l0; l < l0 + RCLEN; ++l){
    ca += base[(size_t)l*64];
    float sn, cs;
    sincosf(ca, &sn, &cs);
    size_t ro = ((size_t)b*LSEQ + l)*128;
    float b1 = Bn[ro+d], b2v = Bn[ro+64+d];
    Bn[ro+d]    = b1*cs - b2v*sn;
    Bn[ro+64+d] = b1*sn + b2v*cs;
    float c1 = Cn[ro+d], c2v = Cn[ro+64+d];
    Cn[ro+d]    = c1*cs - c2v*sn;
    Cn[ro+64+d] = c1*sn + c2v*cs;
  }
}

// ---------------- kernel 4a: chunk-local scan ----------------
__global__ __launch_bounds__(64) void scan_local_kernel(
    const float* __restrict__ dts, const float* __restrict__ alphas,
    const float* __restrict__ lams, const float* __restrict__ xbar,
    const float* __restrict__ Asum,
    const float* __restrict__ Bn, const float* __restrict__ Cn,
    float* __restrict__ ylocal, float* __restrict__ Pfix,
    float* __restrict__ Sfin, float* __restrict__ Dch)
{
  int b  = blockIdx.x / SCHUNK;
  int ch = blockIdx.x % SCHUNK;
  int n  = threadIdx.x;
  float Abar = Asum[0] * (1.f/(float)ROWS);
  float s1 = 0.f, s2 = 0.f, P = 1.f;
  int l0 = ch*SCLEN;
  #pragma unroll
  for (int i = 0; i < SCLEN; ++i){
    int l = l0 + i;
    size_t r = (size_t)b*LSEQ + l;
    float dt = dts[r], lam = lams[r], al = alphas[r], xb = xbar[r];
    float xp = (l > 0) ? xbar[r-1] : 0.f;
    float um = lam*xb + (1.f-lam)*al*xp;
    float dA = expf(dt*Abar);
    float coef = dt*um;
    size_t ro = r*128;
    s1 = dA*s1 + coef*Bn[ro+n];
    s2 = dA*s2 + coef*Bn[ro+64+n];
    P *= dA;
    float p = s1*Cn[ro+n] + s2*Cn[ro+64+n];
    #pragma unroll
    for (int off = 32; off > 0; off >>= 1) p += __shfl_down(p, off);
    if (n == 0){ ylocal[r] = p; Pfix[r] = P; }
  }
  size_t so = ((size_t)b*SCHUNK + ch)*128;
  Sfin[so + n]      = s1;
  Sfin[so + 64 + n] = s2;
  if (n == 0) Dch[b*SCHUNK + ch] = P;
}

// ---------------- kernel 4b: inter-chunk carry ----------------
__global__ __launch_bounds__(128) void scan_carry_kernel(
    const float* __restrict__ Sfin, const float* __restrict__ Dch,
    float* __restrict__ Sin)
{
  int b = blockIdx.x;
  int n = threadIdx.x;   // 0..127
  float s = 0.f;
  for (int c = 0; c < SCHUNK; ++c){
    size_t so = ((size_t)b*SCHUNK + c)*128;
    Sin[so + n] = s;
    s = Dch[b*SCHUNK + c]*s + Sfin[so + n];
  }
}

// ---------------- kernel 4c: fixup  y = y_local + P_l * (C_l . Sin) --------
__global__ __launch_bounds__(256) void scan_fix_kernel(
    const float* __restrict__ Cn, const float* __restrict__ Sin,
    const float* __restrict__ ylocal, const float* __restrict__ Pfix,
    float* __restrict__ outsv)
{
  int r = blockIdx.x*4 + (threadIdx.x>>6);
  int n = threadIdx.x & 63;
  int b  = r / LSEQ;
  int ch = (r % LSEQ) / SCLEN;
  const float* si = Sin + ((size_t)b*SCHUNK + ch)*128;
  size_t ro = (size_t)r*128;
  float p = Cn[ro+n]*si[n] + Cn[ro+64+n]*si[64+n];
  #pragma unroll
  for (int off = 32; off > 0; off >>= 1) p += __shfl_down(p, off);
  if (n == 0) outsv[r] = ylocal[r] + Pfix[r]*p;
}

// ---------------- launch ----------------
extern "C" void kernel_launch(void* const* d_in, const int* in_sizes, int n_in,
                              void* d_out, int out_size, void* d_ws, size_t ws_size,
                              hipStream_t stream)
{
  const float* u    = (const float*)d_in[0];
  const float* W_in = (const float*)d_in[1];
  const float* wnB  = (const float*)d_in[2];
  const float* wnC  = (const float*)d_in[3];
  const float* Bb   = (const float*)d_in[4];
  const float* Cb   = (const float*)d_in[5];
  const float* dtb  = (const float*)d_in[6];
  const float* Alog = (const float*)d_in[7];
  const float* Wout = (const float*)d_in[8];
  float* out = (float*)d_out;
  char* ws = (char*)d_ws;

  constexpr size_t OFF_ASUM = 0;
  constexpr size_t OFF_UBF  = 256;
  constexpr size_t SZ_UBF   = (size_t)ROWS*LDU*2;
  constexpr size_t OFF_WIN  = OFF_UBF + SZ_UBF;
  constexpr size_t SZ_WIN   = (size_t)ZPAD*LDU*2;
  constexpr size_t OFF_WOUT = OFF_WIN + SZ_WIN;
  constexpr size_t SZ_WOUT  = (size_t)DMODEL*LDG*2;
  constexpr size_t OFF_G    = OFF_WOUT + SZ_WOUT;
  constexpr size_t SZ_G     = (size_t)ROWS*LDG*2;
  constexpr size_t OFF_ZS   = OFF_G + SZ_G;
  constexpr size_t SZ_ZS    = (size_t)ROWS*384*4;
  constexpr size_t OFF_BN   = OFF_ZS + SZ_ZS;
  constexpr size_t SZ_BN    = (size_t)ROWS*128*4;
  constexpr size_t OFF_CN   = OFF_BN + SZ_BN;
  constexpr size_t OFF_DTTH = OFF_CN + SZ_BN;
  constexpr size_t SZ_DTTH  = (size_t)ROWS*64*4;
  constexpr size_t OFF_XRAW = OFF_DTTH + SZ_DTTH;
  constexpr size_t OFF_DT   = OFF_XRAW + (size_t)ROWS*4;
  constexpr size_t OFF_AL   = OFF_DT  + (size_t)ROWS*4;
  constexpr size_t OFF_LAM  = OFF_AL  + (size_t)ROWS*4;
  constexpr size_t OFF_XB   = OFF_LAM + (size_t)ROWS*4;
  constexpr size_t OFF_OUTS = OFF_XB  + (size_t)ROWS*4;
  constexpr size_t OFF_YLOC = OFF_OUTS + (size_t)ROWS*4;
  constexpr size_t OFF_PFIX = OFF_YLOC + (size_t)ROWS*4;
  constexpr size_t OFF_SFIN = OFF_PFIX + (size_t)ROWS*4;
  constexpr size_t SZ_SFIN  = (size_t)B_SZ*SCHUNK*128*4;
  constexpr size_t OFF_DCH  = OFF_SFIN + SZ_SFIN;
  constexpr size_t OFF_SIN  = OFF_DCH + (size_t)B_SZ*SCHUNK*4;
  constexpr size_t OFF_CSUM = OFF_SIN + SZ_SFIN;

  float*  Asum   = (float*) (ws + OFF_ASUM);
  bf16_t* ubf    = (bf16_t*)(ws + OFF_UBF);
  bf16_t* winbf  = (bf16_t*)(ws + OFF_WIN);
  bf16_t* woutbf = (bf16_t*)(ws + OFF_WOUT);
  bf16_t* gbuf   = (bf16_t*)(ws + OFF_G);
  float*  zsb    = (float*) (ws + OFF_ZS);
  float*  Bn     = (float*) (ws + OFF_BN);
  float*  Cn     = (float*) (ws + OFF_CN);
  float*  dtth   = (float*) (ws + OFF_DTTH);
  float*  xraw   = (float*) (ws + OFF_XRAW);
  float*  dts    = (float*) (ws + OFF_DT);
  float*  alphas = (float*) (ws + OFF_AL);
  float*  lams   = (float*) (ws + OFF_LAM);
  float*  xbar   = (float*) (ws + OFF_XB);
  float*  outsv  = (float*) (ws + OFF_OUTS);
  float*  ylocal = (float*) (ws + OFF_YLOC);
  float*  Pfix   = (float*) (ws + OFF_PFIX);
  float*  Sfin   = (float*) (ws + OFF_SFIN);
  float*  Dch    = (float*) (ws + OFF_DCH);
  float*  Sin    = (float*) (ws + OFF_SIN);
  float*  csum   = (float*) (ws + OFF_CSUM);

  {
    size_t total4 = ((size_t)ROWS*DMODEL + (size_t)ZPAD*DMODEL + (size_t)DMODEL*EDIM)/4;
    int blocks = (int)((total4 + 255)/256);
    prep_kernel<<<blocks, 256, 0, stream>>>(
        (const float4*)u, (const float4*)W_in, (const float4*)Wout,
        ubf, winbf, woutbf, Asum, xraw);
  }
  // GEMM1: 256x256 tile. grid = 18 x 32 = 576 blocks (nwg%8==0)
  gemmQ_kernel<256, 256, 2, 4, DMODEL/64, ZPAD/256, 0>
      <<<(ZPAD/256)*(ROWS/256), 512, 0, stream>>>(
      ubf, LDU, winbf, LDU, xraw, gbuf, zsb, nullptr, nullptr);
  fuse_kernel<<<ROWS, 128, 0, stream>>>(xraw, zsb, wnB, wnC, Bb, Cb, dtb, Alog,
                                        Bn, Cn, dtth, dts, alphas, lams, xbar, Asum);
  rope_sum_kernel<<<B_SZ*RCH, 64, 0, stream>>>(dtth, csum);
  rope_prefix_kernel<<<B_SZ, 64, 0, stream>>>(csum);
  rope_apply_kernel<<<B_SZ*RCH, 64, 0, stream>>>(dtth, csum, Bn, Cn);
  scan_local_kernel<<<B_SZ*SCHUNK, 64, 0, stream>>>(dts, alphas, lams, xbar, Asum,
                                                    Bn, Cn, ylocal, Pfix, Sfin, Dch);
  scan_carry_kernel<<<B_SZ, 128, 0, stream>>>(Sfin, Dch, Sin);
  scan_fix_kernel<<<ROWS/4, 256, 0, stream>>>(Cn, Sin, ylocal, Pfix, outsv);
  // GEMM2: 256x128 tile. grid = 8 x 32 = 256 blocks = 1/CU
  gemmQ_kernel<256, 128, 4, 2, EDIM/64, DMODEL/128, 1>
      <<<(DMODEL/128)*(ROWS/256), 512, 0, stream>>>(
      gbuf, LDG, woutbf, LDG, nullptr, nullptr, nullptr, outsv, out);
}